// Round 2
// baseline (3306.723 us; speedup 1.0000x reference)
//
#include <hip/hip_runtime.h>

#define L_SZ   4096
#define B_SZ   4
#define NCOLS  16384      // B_SZ * L_SZ
#define DIM    768
#define DINNER 1536
#define E2     3072       // 2*DINNER
#define DTRANK 48
#define DSTATE 16

typedef unsigned short ushortT;
typedef __attribute__((ext_vector_type(8))) short short8;
typedef __attribute__((ext_vector_type(4))) float floatx4;

__device__ __forceinline__ unsigned short f2bf(float f) {
  union { float f; unsigned u; } v; v.f = f;
  unsigned r = v.u + 0x7FFF + ((v.u >> 16) & 1);
  return (unsigned short)(r >> 16);
}
__device__ __forceinline__ float bf2f(unsigned short h) {
  union { unsigned u; float f; } v; v.u = ((unsigned)h) << 16;
  return v.f;
}

// ---------------- fp32 -> bf16 conversion ----------------
__global__ __launch_bounds__(256) void cvt_bf16_kernel(const float* __restrict__ in,
                                                       ushortT* __restrict__ out, int n4) {
  int i = blockIdx.x * 256 + threadIdx.x;
  if (i >= n4) return;
  float4 v = ((const float4*)in)[i];
  ushort4 o;
  o.x = f2bf(v.x); o.y = f2bf(v.y); o.z = f2bf(v.z); o.w = f2bf(v.w);
  ((ushort4*)out)[i] = o;
}

// ---------------- bf16 NT GEMM: C[m,n] = sum_k A[m,k]*B[n,k] ----------------
// A: M x K row-major bf16, B: N x K row-major bf16. M,N % 128 == 0, K % 64 == 0.
__global__ __launch_bounds__(256) void gemm_nt(const ushortT* __restrict__ A,
                                               const ushortT* __restrict__ Bm,
                                               float* __restrict__ Cf, ushortT* __restrict__ Cb,
                                               int M, int N, int K, int out_bf16)
{
  __shared__ ushortT As[128 * 64];
  __shared__ ushortT Bs[128 * 64];
  int tid = threadIdx.x;
  int wave = tid >> 6, lane = tid & 63;
  int bn = blockIdx.x, bm = blockIdx.y;
  const ushortT* Abase = A + (size_t)bm * 128 * K;
  const ushortT* Bbase = Bm + (size_t)bn * 128 * K;
  int lm = lane & 15, lq = lane >> 4;
  int wm = (wave >> 1) * 64, wn = (wave & 1) * 64;
  int rloc = lane >> 3;           // 0..7 row within staging instr
  int c_st = (lane & 7) * 8;      // bf16 elem offset of 16B chunk
  floatx4 acc[4][4] = {};

  for (int k0 = 0; k0 < K; k0 += 64) {
    __syncthreads();
    #pragma unroll
    for (int j = 0; j < 4; j++) {
      int t = wave * 4 + j;                 // staging instr id 0..15 -> rows t*8..t*8+7
      const ushortT* ga = Abase + (size_t)(t * 8 + rloc) * K + k0 + c_st;
      const ushortT* gb = Bbase + (size_t)(t * 8 + rloc) * K + k0 + c_st;
      __builtin_amdgcn_global_load_lds((const __attribute__((address_space(1))) void*)ga,
                                       (__attribute__((address_space(3))) void*)(As + t * 512),
                                       16, 0, 0);
      __builtin_amdgcn_global_load_lds((const __attribute__((address_space(1))) void*)gb,
                                       (__attribute__((address_space(3))) void*)(Bs + t * 512),
                                       16, 0, 0);
    }
    __syncthreads();
    #pragma unroll
    for (int ks = 0; ks < 2; ks++) {
      short8 af[4], bfv[4];
      #pragma unroll
      for (int i = 0; i < 4; i++)
        af[i] = *(const short8*)(As + (wm + i * 16 + lm) * 64 + ks * 32 + lq * 8);
      #pragma unroll
      for (int j2 = 0; j2 < 4; j2++)
        bfv[j2] = *(const short8*)(Bs + (wn + j2 * 16 + lm) * 64 + ks * 32 + lq * 8);
      #pragma unroll
      for (int i = 0; i < 4; i++)
        #pragma unroll
        for (int j2 = 0; j2 < 4; j2++)
          acc[i][j2] = __builtin_amdgcn_mfma_f32_16x16x32_bf16(af[i], bfv[j2], acc[i][j2], 0, 0, 0);
    }
  }
  #pragma unroll
  for (int i = 0; i < 4; i++) {
    #pragma unroll
    for (int j2 = 0; j2 < 4; j2++) {
      int mg = bm * 128 + wm + i * 16 + lq * 4;
      int ng = bn * 128 + wn + j2 * 16 + lm;
      #pragma unroll
      for (int q = 0; q < 4; q++) {
        size_t off = (size_t)(mg + q) * N + ng;
        if (out_bf16) Cb[off] = f2bf(acc[i][j2][q]);
        else          Cf[off] = acc[i][j2][q];
      }
    }
  }
}

// ---------------- causal depthwise conv(k=4) + silu, bf16 in/out ----------------
__global__ __launch_bounds__(256) void conv_silu_kernel(const ushortT* __restrict__ xz,
                                                        const float* __restrict__ w,
                                                        const float* __restrict__ bias,
                                                        ushortT* __restrict__ xc, int reverse)
{
  int idx = blockIdx.x * 256 + threadIdx.x;   // each thread: 4 outputs
  int l0 = (idx & 1023) << 2;
  int rb = idx >> 10;                         // d*4 + b
  int b = rb & 3, d = rb >> 2;
  const ushortT* xin = xz + (size_t)d * NCOLS + b * L_SZ;
  float w0 = w[d * 4], w1 = w[d * 4 + 1], w2 = w[d * 4 + 2], w3 = w[d * 4 + 3];
  float bv = bias[d];
  float xv[8];
  float r0, r1, r2, r3;
  if (!reverse) {
    if (l0 >= 4) {
      ushort4 a = *(const ushort4*)(xin + l0 - 4);
      ushort4 c = *(const ushort4*)(xin + l0);
      xv[0]=bf2f(a.x); xv[1]=bf2f(a.y); xv[2]=bf2f(a.z); xv[3]=bf2f(a.w);
      xv[4]=bf2f(c.x); xv[5]=bf2f(c.y); xv[6]=bf2f(c.z); xv[7]=bf2f(c.w);
    } else {
      #pragma unroll
      for (int i = 0; i < 8; i++) { int p = l0 - 4 + i; xv[i] = (p >= 0) ? bf2f(xin[p]) : 0.f; }
    }
    r0 = bv + w0*xv[1] + w1*xv[2] + w2*xv[3] + w3*xv[4];
    r1 = bv + w0*xv[2] + w1*xv[3] + w2*xv[4] + w3*xv[5];
    r2 = bv + w0*xv[3] + w1*xv[4] + w2*xv[5] + w3*xv[6];
    r3 = bv + w0*xv[4] + w1*xv[5] + w2*xv[6] + w3*xv[7];
  } else {
    int base = 4092 - l0;                     // xv[i] = xin[base+i]
    if (l0 >= 4) {
      ushort4 a = *(const ushort4*)(xin + base);
      ushort4 c = *(const ushort4*)(xin + base + 4);
      xv[0]=bf2f(a.x); xv[1]=bf2f(a.y); xv[2]=bf2f(a.z); xv[3]=bf2f(a.w);
      xv[4]=bf2f(c.x); xv[5]=bf2f(c.y); xv[6]=bf2f(c.z); xv[7]=bf2f(c.w);
    } else {
      #pragma unroll
      for (int i = 0; i < 8; i++) { int p = base + i; xv[i] = (p <= 4095) ? bf2f(xin[p]) : 0.f; }
    }
    r0 = bv + w0*xv[6] + w1*xv[5] + w2*xv[4] + w3*xv[3];
    r1 = bv + w0*xv[5] + w1*xv[4] + w2*xv[3] + w3*xv[2];
    r2 = bv + w0*xv[4] + w1*xv[3] + w2*xv[2] + w3*xv[1];
    r3 = bv + w0*xv[3] + w1*xv[2] + w2*xv[1] + w3*xv[0];
  }
  ushort4 o;
  o.x = f2bf(r0 / (1.f + __expf(-r0)));
  o.y = f2bf(r1 / (1.f + __expf(-r1)));
  o.z = f2bf(r2 / (1.f + __expf(-r2)));
  o.w = f2bf(r3 / (1.f + __expf(-r3)));
  *(ushort4*)(xc + (size_t)d * NCOLS + b * L_SZ + l0) = o;
}

// ---------------- x_proj GEMM (fp32 vector): 80 x NCOLS from xc(bf16) ----------------
__global__ __launch_bounds__(256) void xdbl_kernel(const ushortT* __restrict__ xc,
                                                   const float* __restrict__ W, // (80,1536)
                                                   float* __restrict__ dtr,
                                                   float* __restrict__ Bt,
                                                   float* __restrict__ Ct)
{
  __shared__ float xcs[32 * 68];   // +4 pad
  __shared__ float Ws[80 * 32];
  int tid = threadIdx.x;
  int n0 = blockIdx.x * 64;
  int tm = tid >> 4, tn = tid & 15;
  float acc[5][4] = {};
  for (int k0 = 0; k0 < DINNER; k0 += 32) {
    __syncthreads();
    {
      int kk = tid >> 3, c8 = (tid & 7) * 8;
      const ushortT* src = xc + (size_t)(k0 + kk) * NCOLS + n0 + c8;
      ushort4 a = *(const ushort4*)src;
      ushort4 b = *(const ushort4*)(src + 4);
      float* dst = xcs + kk * 68 + c8;
      dst[0]=bf2f(a.x); dst[1]=bf2f(a.y); dst[2]=bf2f(a.z); dst[3]=bf2f(a.w);
      dst[4]=bf2f(b.x); dst[5]=bf2f(b.y); dst[6]=bf2f(b.z); dst[7]=bf2f(b.w);
    }
    for (int i = tid; i < 80 * 32; i += 256) {
      int m = i >> 5, kk = i & 31;
      Ws[i] = W[(size_t)m * DINNER + k0 + kk];
    }
    __syncthreads();
    #pragma unroll 8
    for (int kk = 0; kk < 32; kk++) {
      const float* xr = xcs + kk * 68 + tn * 4;
      float x0 = xr[0], x1 = xr[1], x2 = xr[2], x3 = xr[3];
      #pragma unroll
      for (int im = 0; im < 5; im++) {
        float wv = Ws[(tm * 5 + im) * 32 + kk];
        acc[im][0] += wv * x0; acc[im][1] += wv * x1;
        acc[im][2] += wv * x2; acc[im][3] += wv * x3;
      }
    }
  }
  #pragma unroll
  for (int im = 0; im < 5; im++) {
    int m = tm * 5 + im;
    #pragma unroll
    for (int j = 0; j < 4; j++) {
      int n = n0 + tn * 4 + j;
      float v = acc[im][j];
      if (m < 48)      dtr[(size_t)m * NCOLS + n] = v;
      else if (m < 64) Bt[(size_t)n * 16 + (m - 48)] = v;
      else             Ct[(size_t)n * 16 + (m - 64)] = v;
    }
  }
}

// ---------------- dt = softplus(dt_w @ dtr + bias), bf16 out ----------------
__global__ __launch_bounds__(256) void dt_kernel(const float* __restrict__ dtr,
                                                 const float* __restrict__ W, // (1536,48)
                                                 const float* __restrict__ bias,
                                                 ushortT* __restrict__ dtb)
{
  __shared__ float s[48 * 64];
  int tid = threadIdx.x;
  int n0 = blockIdx.x * 64;
  for (int i = tid; i < 48 * 64; i += 256) {
    int r = i >> 6, c = i & 63;
    s[i] = dtr[(size_t)r * NCOLS + n0 + c];
  }
  __syncthreads();
  int n = tid & 63;
  for (int d = tid >> 6; d < DINNER; d += 4) {
    float accv = bias[d];
    const float* wr = W + (size_t)d * 48;
    #pragma unroll 12
    for (int r = 0; r < 48; r++) accv += wr[r] * s[r * 64 + n];
    float sp = (accv > 20.f) ? accv : log1pf(__expf(accv));
    dtb[(size_t)d * NCOLS + n0 + n] = f2bf(sp);
  }
}

// ---------------- selective scan: lane = (b,d,nstate); 16-lane shuffle reduce ----------------
// y stored as bf16; reverse pass does RMW-add at original (un-reversed) positions.
__global__ __launch_bounds__(256) void scan_kernel(const ushortT* __restrict__ u,
                                                   const ushortT* __restrict__ dt,
                                                   const float* __restrict__ Bt,
                                                   const float* __restrict__ Ct,
                                                   const float* __restrict__ A_log,
                                                   const float* __restrict__ Dp,
                                                   ushortT* __restrict__ y, int reverse)
{
  int tid = blockIdx.x * 256 + threadIdx.x;
  int ns = tid & 15;
  int ch = tid >> 4;                 // 0..6143
  int d = ch % DINNER, b = ch / DINNER;
  float Av = -__expf(A_log[d * 16 + ns]);
  float Dv = Dp[d];
  const ushortT* ur  = u  + (size_t)d * NCOLS + b * L_SZ;
  const ushortT* tr  = dt + (size_t)d * NCOLS + b * L_SZ;
  const float* Bp = Bt + (size_t)b * L_SZ * 16;
  const float* Cp = Ct + (size_t)b * L_SZ * 16;
  ushortT* yr = y + (size_t)d * NCOLS + b * L_SZ;
  float h = 0.f;
  for (int l0 = 0; l0 < L_SZ; l0 += 4) {
    ushort4 u4 = *(const ushort4*)(ur + l0);
    ushort4 t4 = *(const ushort4*)(tr + l0);
    float uv[4] = { bf2f(u4.x), bf2f(u4.y), bf2f(u4.z), bf2f(u4.w) };
    float tv[4] = { bf2f(t4.x), bf2f(t4.y), bf2f(t4.z), bf2f(t4.w) };
    float yo[4];
    #pragma unroll
    for (int q = 0; q < 4; q++) {
      int l = l0 + q;
      float Bv = Bp[l * 16 + ns];
      float Cv = Cp[l * 16 + ns];
      float dA = __expf(tv[q] * Av);
      h = h * dA + tv[q] * Bv * uv[q];
      float part = h * Cv;
      part += __shfl_xor(part, 1);
      part += __shfl_xor(part, 2);
      part += __shfl_xor(part, 4);
      part += __shfl_xor(part, 8);
      yo[q] = part + Dv * uv[q];
    }
    if (ns == 0) {
      if (!reverse) {
        ushort4 o;
        o.x = f2bf(yo[0]); o.y = f2bf(yo[1]); o.z = f2bf(yo[2]); o.w = f2bf(yo[3]);
        *(ushort4*)(yr + l0) = o;
      } else {
        ushort4* dst = (ushort4*)(yr + (4092 - l0));   // orig pos 4095-l
        ushort4 old = *dst;
        ushort4 o;
        o.x = f2bf(bf2f(old.x) + yo[3]);
        o.y = f2bf(bf2f(old.y) + yo[2]);
        o.z = f2bf(bf2f(old.z) + yo[1]);
        o.w = f2bf(bf2f(old.w) + yo[0]);
        *dst = o;
      }
    }
  }
}

// ---------------- inner = bf16( y * silu(z) ), transposed to (n, d) ----------------
__global__ __launch_bounds__(256) void inner_kernel(const ushortT* __restrict__ y,
                                                    const ushortT* __restrict__ xz,
                                                    ushortT* __restrict__ innerb)
{
  __shared__ float tile[64 * 65];
  int n0 = blockIdx.x * 64, d0 = blockIdx.y * 64;
  int tid = threadIdx.x;
  int c = tid & 63, rq = tid >> 6;
  #pragma unroll
  for (int r = 0; r < 16; r++) {
    int dd = rq + r * 4;
    float yv = bf2f(y[(size_t)(d0 + dd) * NCOLS + n0 + c]);
    float zv = bf2f(xz[(size_t)(DINNER + d0 + dd) * NCOLS + n0 + c]);
    float sv = zv / (1.f + __expf(-zv));
    tile[dd * 65 + c] = yv * sv;
  }
  __syncthreads();
  #pragma unroll
  for (int r = 0; r < 16; r++) {
    int nn = rq + r * 4;
    innerb[(size_t)(n0 + nn) * DINNER + d0 + c] = f2bf(tile[c * 65 + nn]);
  }
}

extern "C" void kernel_launch(void* const* d_in, const int* in_sizes, int n_in,
                              void* d_out, int out_size, void* d_ws, size_t ws_size,
                              hipStream_t stream)
{
  const float* x          = (const float*)d_in[0];
  const float* in_proj_w  = (const float*)d_in[1];
  const float* out_proj_w = (const float*)d_in[2];
  const float* conv_w     = (const float*)d_in[3];
  const float* conv_b     = (const float*)d_in[4];
  const float* xproj_w    = (const float*)d_in[5];
  const float* dt_w       = (const float*)d_in[6];
  const float* dt_b       = (const float*)d_in[7];
  const float* A_log      = (const float*)d_in[8];
  const float* Dp         = (const float*)d_in[9];
  const float* conv_w_b   = (const float*)d_in[10];
  const float* conv_b_b   = (const float*)d_in[11];
  const float* xproj_w_b  = (const float*)d_in[12];
  const float* dt_w_b     = (const float*)d_in[13];
  const float* dt_b_b     = (const float*)d_in[14];
  const float* A_log_b    = (const float*)d_in[15];
  const float* D_b        = (const float*)d_in[16];

  // --- workspace layout (peak 199.25 MiB) ---
  // [0,96M)      XZ bf16 (3072 x 16384); first half later reused as INNER (n,d)
  // [96M,144M)   XC bf16 (1536 x 16384); holds XB (24M) during P0/P1
  // [144M,192M)  YB bf16 (1536 x 16384); holds WIB (4.5M) during P0/P1
  // [192M,...)   DTR fp32 (3M) | BT (1M) | CT (1M) | WOB bf16 (2.25M)
  // DTB bf16 (48M) lives in d_out (dead before final GEMM writes d_out).
  char* ws = (char*)d_ws;
  ushortT* XZ   = (ushortT*)(ws + 0);
  ushortT* XC   = (ushortT*)(ws + 100663296);
  ushortT* YB   = (ushortT*)(ws + 150994944);
  float*   DTR  = (float*)  (ws + 201326592);
  float*   BT   = (float*)  (ws + 204472320);
  float*   CT   = (float*)  (ws + 205520896);
  ushortT* WOB  = (ushortT*)(ws + 206569472);
  ushortT* XB   = (ushortT*)(ws + 100663296);  // overlay on XC region (P0/P1 only)
  ushortT* WIB  = (ushortT*)(ws + 150994944);  // overlay on YB region (P0/P1 only)
  ushortT* DTB  = (ushortT*)d_out;             // 48 MiB exactly
  ushortT* INNER = XZ;                         // overlay on XZ x-half (after conv/scans)
  float* OUT = (float*)d_out;

  // bf16 conversions
  cvt_bf16_kernel<<<12288, 256, 0, stream>>>(x, XB, 3145728);
  cvt_bf16_kernel<<<2304, 256, 0, stream>>>(in_proj_w, WIB, 589824);
  cvt_bf16_kernel<<<1152, 256, 0, stream>>>(out_proj_w, WOB, 294912);

  // xz = in_proj_w @ x^T : (3072 x 16384), bf16 out
  gemm_nt<<<dim3(128, 24), 256, 0, stream>>>(WIB, XB, nullptr, XZ, E2, NCOLS, DIM, 1);

  // forward direction
  conv_silu_kernel<<<24576, 256, 0, stream>>>(XZ, conv_w, conv_b, XC, 0);
  xdbl_kernel<<<256, 256, 0, stream>>>(XC, xproj_w, DTR, BT, CT);
  dt_kernel<<<256, 256, 0, stream>>>(DTR, dt_w, dt_b, DTB);
  scan_kernel<<<384, 256, 0, stream>>>(XC, DTB, BT, CT, A_log, Dp, YB, 0);

  // reverse direction (reversed coords; y added at original positions)
  conv_silu_kernel<<<24576, 256, 0, stream>>>(XZ, conv_w_b, conv_b_b, XC, 1);
  xdbl_kernel<<<256, 256, 0, stream>>>(XC, xproj_w_b, DTR, BT, CT);
  dt_kernel<<<256, 256, 0, stream>>>(DTR, dt_w_b, dt_b_b, DTB);
  scan_kernel<<<384, 256, 0, stream>>>(XC, DTB, BT, CT, A_log_b, D_b, YB, 1);

  // inner = bf16( y * silu(z) ) transposed to (n, d); writes XZ x-half, reads z-half
  inner_kernel<<<dim3(256, 24), 256, 0, stream>>>(YB, XZ, INNER);

  // out = inner @ out_proj_w^T : (16384 x 768), fp32 out
  gemm_nt<<<dim3(6, 128), 256, 0, stream>>>(INNER, WOB, OUT, nullptr, NCOLS, DIM, DINNER, 0);
}

// Round 3
// 3169.015 us; speedup vs baseline: 1.0435x; 1.0435x over previous
//
#include <hip/hip_runtime.h>

#define L_SZ   4096
#define B_SZ   4
#define NCOLS  16384      // B_SZ * L_SZ
#define DIM    768
#define DINNER 1536
#define E2     3072       // 2*DINNER
#define DTRANK 48
#define DSTATE 16
#define NCHUNK 32
#define CLEN   128        // L_SZ / NCHUNK

typedef unsigned short ushortT;
typedef __attribute__((ext_vector_type(8))) short short8;
typedef __attribute__((ext_vector_type(4))) float floatx4;

__device__ __forceinline__ unsigned short f2bf(float f) {
  union { float f; unsigned u; } v; v.f = f;
  unsigned r = v.u + 0x7FFF + ((v.u >> 16) & 1);
  return (unsigned short)(r >> 16);
}
__device__ __forceinline__ float bf2f(unsigned short h) {
  union { unsigned u; float f; } v; v.u = ((unsigned)h) << 16;
  return v.f;
}

// ---------------- fp32 -> bf16 conversion ----------------
__global__ __launch_bounds__(256) void cvt_bf16_kernel(const float* __restrict__ in,
                                                       ushortT* __restrict__ out, int n4) {
  int i = blockIdx.x * 256 + threadIdx.x;
  if (i >= n4) return;
  float4 v = ((const float4*)in)[i];
  ushort4 o;
  o.x = f2bf(v.x); o.y = f2bf(v.y); o.z = f2bf(v.z); o.w = f2bf(v.w);
  ((ushort4*)out)[i] = o;
}

// ---------------- bf16 NT GEMM: C[m,n] = sum_k A[m,k]*B[n,k] ----------------
__global__ __launch_bounds__(256) void gemm_nt(const ushortT* __restrict__ A,
                                               const ushortT* __restrict__ Bm,
                                               float* __restrict__ Cf, ushortT* __restrict__ Cb,
                                               int M, int N, int K, int out_bf16)
{
  __shared__ ushortT As[128 * 64];
  __shared__ ushortT Bs[128 * 64];
  int tid = threadIdx.x;
  int wave = tid >> 6, lane = tid & 63;
  int bn = blockIdx.x, bm = blockIdx.y;
  const ushortT* Abase = A + (size_t)bm * 128 * K;
  const ushortT* Bbase = Bm + (size_t)bn * 128 * K;
  int lm = lane & 15, lq = lane >> 4;
  int wm = (wave >> 1) * 64, wn = (wave & 1) * 64;
  int rloc = lane >> 3;
  int c_st = (lane & 7) * 8;
  floatx4 acc[4][4] = {};

  for (int k0 = 0; k0 < K; k0 += 64) {
    __syncthreads();
    #pragma unroll
    for (int j = 0; j < 4; j++) {
      int t = wave * 4 + j;
      const ushortT* ga = Abase + (size_t)(t * 8 + rloc) * K + k0 + c_st;
      const ushortT* gb = Bbase + (size_t)(t * 8 + rloc) * K + k0 + c_st;
      __builtin_amdgcn_global_load_lds((const __attribute__((address_space(1))) void*)ga,
                                       (__attribute__((address_space(3))) void*)(As + t * 512),
                                       16, 0, 0);
      __builtin_amdgcn_global_load_lds((const __attribute__((address_space(1))) void*)gb,
                                       (__attribute__((address_space(3))) void*)(Bs + t * 512),
                                       16, 0, 0);
    }
    __syncthreads();
    #pragma unroll
    for (int ks = 0; ks < 2; ks++) {
      short8 af[4], bfv[4];
      #pragma unroll
      for (int i = 0; i < 4; i++)
        af[i] = *(const short8*)(As + (wm + i * 16 + lm) * 64 + ks * 32 + lq * 8);
      #pragma unroll
      for (int j2 = 0; j2 < 4; j2++)
        bfv[j2] = *(const short8*)(Bs + (wn + j2 * 16 + lm) * 64 + ks * 32 + lq * 8);
      #pragma unroll
      for (int i = 0; i < 4; i++)
        #pragma unroll
        for (int j2 = 0; j2 < 4; j2++)
          acc[i][j2] = __builtin_amdgcn_mfma_f32_16x16x32_bf16(af[i], bfv[j2], acc[i][j2], 0, 0, 0);
    }
  }
  #pragma unroll
  for (int i = 0; i < 4; i++) {
    #pragma unroll
    for (int j2 = 0; j2 < 4; j2++) {
      int mg = bm * 128 + wm + i * 16 + lq * 4;
      int ng = bn * 128 + wn + j2 * 16 + lm;
      #pragma unroll
      for (int q = 0; q < 4; q++) {
        size_t off = (size_t)(mg + q) * N + ng;
        if (out_bf16) Cb[off] = f2bf(acc[i][j2][q]);
        else          Cf[off] = acc[i][j2][q];
      }
    }
  }
}

// ---------------- causal depthwise conv(k=4) + silu, bf16 in/out ----------------
__global__ __launch_bounds__(256) void conv_silu_kernel(const ushortT* __restrict__ xz,
                                                        const float* __restrict__ w,
                                                        const float* __restrict__ bias,
                                                        ushortT* __restrict__ xc, int reverse)
{
  int idx = blockIdx.x * 256 + threadIdx.x;
  int l0 = (idx & 1023) << 2;
  int rb = idx >> 10;
  int b = rb & 3, d = rb >> 2;
  const ushortT* xin = xz + (size_t)d * NCOLS + b * L_SZ;
  float w0 = w[d * 4], w1 = w[d * 4 + 1], w2 = w[d * 4 + 2], w3 = w[d * 4 + 3];
  float bv = bias[d];
  float xv[8];
  float r0, r1, r2, r3;
  if (!reverse) {
    if (l0 >= 4) {
      ushort4 a = *(const ushort4*)(xin + l0 - 4);
      ushort4 c = *(const ushort4*)(xin + l0);
      xv[0]=bf2f(a.x); xv[1]=bf2f(a.y); xv[2]=bf2f(a.z); xv[3]=bf2f(a.w);
      xv[4]=bf2f(c.x); xv[5]=bf2f(c.y); xv[6]=bf2f(c.z); xv[7]=bf2f(c.w);
    } else {
      #pragma unroll
      for (int i = 0; i < 8; i++) { int p = l0 - 4 + i; xv[i] = (p >= 0) ? bf2f(xin[p]) : 0.f; }
    }
    r0 = bv + w0*xv[1] + w1*xv[2] + w2*xv[3] + w3*xv[4];
    r1 = bv + w0*xv[2] + w1*xv[3] + w2*xv[4] + w3*xv[5];
    r2 = bv + w0*xv[3] + w1*xv[4] + w2*xv[5] + w3*xv[6];
    r3 = bv + w0*xv[4] + w1*xv[5] + w2*xv[6] + w3*xv[7];
  } else {
    int base = 4092 - l0;
    if (l0 >= 4) {
      ushort4 a = *(const ushort4*)(xin + base);
      ushort4 c = *(const ushort4*)(xin + base + 4);
      xv[0]=bf2f(a.x); xv[1]=bf2f(a.y); xv[2]=bf2f(a.z); xv[3]=bf2f(a.w);
      xv[4]=bf2f(c.x); xv[5]=bf2f(c.y); xv[6]=bf2f(c.z); xv[7]=bf2f(c.w);
    } else {
      #pragma unroll
      for (int i = 0; i < 8; i++) { int p = base + i; xv[i] = (p <= 4095) ? bf2f(xin[p]) : 0.f; }
    }
    r0 = bv + w0*xv[6] + w1*xv[5] + w2*xv[4] + w3*xv[3];
    r1 = bv + w0*xv[5] + w1*xv[4] + w2*xv[3] + w3*xv[2];
    r2 = bv + w0*xv[4] + w1*xv[3] + w2*xv[2] + w3*xv[1];
    r3 = bv + w0*xv[3] + w1*xv[2] + w2*xv[1] + w3*xv[0];
  }
  ushort4 o;
  o.x = f2bf(r0 / (1.f + __expf(-r0)));
  o.y = f2bf(r1 / (1.f + __expf(-r1)));
  o.z = f2bf(r2 / (1.f + __expf(-r2)));
  o.w = f2bf(r3 / (1.f + __expf(-r3)));
  *(ushort4*)(xc + (size_t)d * NCOLS + b * L_SZ + l0) = o;
}

// ---------------- x_proj GEMM (fp32 vector): 80 x NCOLS from xc(bf16) ----------------
__global__ __launch_bounds__(256) void xdbl_kernel(const ushortT* __restrict__ xc,
                                                   const float* __restrict__ W, // (80,1536)
                                                   float* __restrict__ dtr,
                                                   float* __restrict__ Bt,
                                                   float* __restrict__ Ct)
{
  __shared__ float xcs[32 * 68];
  __shared__ float Ws[80 * 32];
  int tid = threadIdx.x;
  int n0 = blockIdx.x * 64;
  int tm = tid >> 4, tn = tid & 15;
  float acc[5][4] = {};
  for (int k0 = 0; k0 < DINNER; k0 += 32) {
    __syncthreads();
    {
      int kk = tid >> 3, c8 = (tid & 7) * 8;
      const ushortT* src = xc + (size_t)(k0 + kk) * NCOLS + n0 + c8;
      ushort4 a = *(const ushort4*)src;
      ushort4 b = *(const ushort4*)(src + 4);
      float* dst = xcs + kk * 68 + c8;
      dst[0]=bf2f(a.x); dst[1]=bf2f(a.y); dst[2]=bf2f(a.z); dst[3]=bf2f(a.w);
      dst[4]=bf2f(b.x); dst[5]=bf2f(b.y); dst[6]=bf2f(b.z); dst[7]=bf2f(b.w);
    }
    for (int i = tid; i < 80 * 32; i += 256) {
      int m = i >> 5, kk = i & 31;
      Ws[i] = W[(size_t)m * DINNER + k0 + kk];
    }
    __syncthreads();
    #pragma unroll 8
    for (int kk = 0; kk < 32; kk++) {
      const float* xr = xcs + kk * 68 + tn * 4;
      float x0 = xr[0], x1 = xr[1], x2 = xr[2], x3 = xr[3];
      #pragma unroll
      for (int im = 0; im < 5; im++) {
        float wv = Ws[(tm * 5 + im) * 32 + kk];
        acc[im][0] += wv * x0; acc[im][1] += wv * x1;
        acc[im][2] += wv * x2; acc[im][3] += wv * x3;
      }
    }
  }
  #pragma unroll
  for (int im = 0; im < 5; im++) {
    int m = tm * 5 + im;
    #pragma unroll
    for (int j = 0; j < 4; j++) {
      int n = n0 + tn * 4 + j;
      float v = acc[im][j];
      if (m < 48)      dtr[(size_t)m * NCOLS + n] = v;
      else if (m < 64) Bt[(size_t)n * 16 + (m - 48)] = v;
      else             Ct[(size_t)n * 16 + (m - 64)] = v;
    }
  }
}

// ---------------- dt = softplus(dt_w @ dtr + bias), bf16 out ----------------
__global__ __launch_bounds__(256) void dt_kernel(const float* __restrict__ dtr,
                                                 const float* __restrict__ W, // (1536,48)
                                                 const float* __restrict__ bias,
                                                 ushortT* __restrict__ dtb)
{
  __shared__ float s[48 * 64];
  int tid = threadIdx.x;
  int n0 = blockIdx.x * 64;
  for (int i = tid; i < 48 * 64; i += 256) {
    int r = i >> 6, c = i & 63;
    s[i] = dtr[(size_t)r * NCOLS + n0 + c];
  }
  __syncthreads();
  int n = tid & 63;
  for (int d = tid >> 6; d < DINNER; d += 4) {
    float accv = bias[d];
    const float* wr = W + (size_t)d * 48;
    #pragma unroll 12
    for (int r = 0; r < 48; r++) accv += wr[r] * s[r * 64 + n];
    float sp = (accv > 20.f) ? accv : log1pf(__expf(accv));
    dtb[(size_t)d * NCOLS + n0 + n] = f2bf(sp);
  }
}

// ---------------- chunked selective scan (two-pass, block-local combine) ----------------
// Block: 256 threads = 8 d-rows x 32 chunks of 128 steps. All 16 states per thread
// in registers. Pass1: per-chunk (P = prod dA, hp = h from 0). LDS combine gives
// h_start per chunk. Pass2: recompute h from h_start, emit y (fwd: store; rev: RMW-add
// at original positions). Grid: (DINNER/8, B_SZ).
__global__ __launch_bounds__(256) void scan_kernel2(const ushortT* __restrict__ u,
                                                    const ushortT* __restrict__ dt,
                                                    const float* __restrict__ Bt,
                                                    const float* __restrict__ Ct,
                                                    const float* __restrict__ A_log,
                                                    const float* __restrict__ Dp,
                                                    ushortT* __restrict__ y, int reverse)
{
  __shared__ float Ps[8 * NCHUNK * 16];
  __shared__ float Hs[8 * NCHUNK * 16];
  int tid = threadIdx.x;
  int c = tid & 31, dl = tid >> 5;
  int b = blockIdx.y;
  int d = blockIdx.x * 8 + dl;
  int L0 = c * CLEN;

  float Av2[16];
  #pragma unroll
  for (int n = 0; n < 16; n++)
    Av2[n] = -__expf(A_log[d * 16 + n]) * 1.442695040888963f;  // A * log2(e)
  float Dv = Dp[d];

  const ushortT* ur = u  + (size_t)d * NCOLS + b * L_SZ + L0;
  const ushortT* tr = dt + (size_t)d * NCOLS + b * L_SZ + L0;
  const float*   Bp = Bt + ((size_t)b * L_SZ + L0) * 16;
  const float*   Cp = Ct + ((size_t)b * L_SZ + L0) * 16;

  float h[16], P[16];
  #pragma unroll
  for (int n = 0; n < 16; n++) { h[n] = 0.f; P[n] = 1.f; }

  // ---- pass 1: chunk summaries ----
  for (int l0 = 0; l0 < CLEN; l0 += 4) {
    ushort4 u4 = *(const ushort4*)(ur + l0);
    ushort4 t4 = *(const ushort4*)(tr + l0);
    float uv[4] = { bf2f(u4.x), bf2f(u4.y), bf2f(u4.z), bf2f(u4.w) };
    float tv[4] = { bf2f(t4.x), bf2f(t4.y), bf2f(t4.z), bf2f(t4.w) };
    #pragma unroll
    for (int q = 0; q < 4; q++) {
      float dtu = tv[q] * uv[q];
      const float4* bp4 = (const float4*)(Bp + (l0 + q) * 16);
      float4 b0 = bp4[0], b1 = bp4[1], b2 = bp4[2], b3 = bp4[3];
      float Bf[16] = { b0.x,b0.y,b0.z,b0.w, b1.x,b1.y,b1.z,b1.w,
                       b2.x,b2.y,b2.z,b2.w, b3.x,b3.y,b3.z,b3.w };
      #pragma unroll
      for (int n = 0; n < 16; n++) {
        float e = exp2f(tv[q] * Av2[n]);
        h[n] = h[n] * e + Bf[n] * dtu;
        P[n] *= e;
      }
    }
  }

  int base = (dl * NCHUNK + c) * 16;
  #pragma unroll
  for (int n = 0; n < 16; n++) { Ps[base + n] = P[n]; Hs[base + n] = h[n]; }
  __syncthreads();

  // ---- combine: 128 threads, each (d-row, state) scans 32 chunks serially ----
  if (tid < 128) {
    int dl2 = tid >> 4, n2 = tid & 15;
    float hs = 0.f;
    for (int cc = 0; cc < NCHUNK; cc++) {
      int idx = (dl2 * NCHUNK + cc) * 16 + n2;
      float tmp = Hs[idx];
      Hs[idx] = hs;                   // h at chunk start
      hs = Ps[idx] * hs + tmp;        // h at chunk end
    }
  }
  __syncthreads();
  #pragma unroll
  for (int n = 0; n < 16; n++) h[n] = Hs[base + n];

  // ---- pass 2: recompute h from h_start, emit y ----
  ushortT* yr = y + (size_t)d * NCOLS + b * L_SZ;
  for (int l0 = 0; l0 < CLEN; l0 += 4) {
    ushort4 u4 = *(const ushort4*)(ur + l0);
    ushort4 t4 = *(const ushort4*)(tr + l0);
    float uv[4] = { bf2f(u4.x), bf2f(u4.y), bf2f(u4.z), bf2f(u4.w) };
    float tv[4] = { bf2f(t4.x), bf2f(t4.y), bf2f(t4.z), bf2f(t4.w) };
    float yo[4];
    #pragma unroll
    for (int q = 0; q < 4; q++) {
      float dtu = tv[q] * uv[q];
      const float4* bp4 = (const float4*)(Bp + (l0 + q) * 16);
      const float4* cp4 = (const float4*)(Cp + (l0 + q) * 16);
      float4 b0 = bp4[0], b1 = bp4[1], b2 = bp4[2], b3 = bp4[3];
      float4 c0 = cp4[0], c1 = cp4[1], c2 = cp4[2], c3 = cp4[3];
      float Bf[16] = { b0.x,b0.y,b0.z,b0.w, b1.x,b1.y,b1.z,b1.w,
                       b2.x,b2.y,b2.z,b2.w, b3.x,b3.y,b3.z,b3.w };
      float Cf[16] = { c0.x,c0.y,c0.z,c0.w, c1.x,c1.y,c1.z,c1.w,
                       c2.x,c2.y,c2.z,c2.w, c3.x,c3.y,c3.z,c3.w };
      float acc = 0.f;
      #pragma unroll
      for (int n = 0; n < 16; n++) {
        float e = exp2f(tv[q] * Av2[n]);
        h[n] = h[n] * e + Bf[n] * dtu;
        acc += h[n] * Cf[n];
      }
      yo[q] = acc + Dv * uv[q];
    }
    if (!reverse) {
      ushort4 o;
      o.x = f2bf(yo[0]); o.y = f2bf(yo[1]); o.z = f2bf(yo[2]); o.w = f2bf(yo[3]);
      *(ushort4*)(yr + L0 + l0) = o;
    } else {
      ushort4* dst = (ushort4*)(yr + (4092 - (L0 + l0)));  // orig pos 4095-l
      ushort4 old = *dst;
      ushort4 o;
      o.x = f2bf(bf2f(old.x) + yo[3]);
      o.y = f2bf(bf2f(old.y) + yo[2]);
      o.z = f2bf(bf2f(old.z) + yo[1]);
      o.w = f2bf(bf2f(old.w) + yo[0]);
      *dst = o;
    }
  }
}

// ---------------- inner = bf16( y * silu(z) ), transposed to (n, d) ----------------
__global__ __launch_bounds__(256) void inner_kernel(const ushortT* __restrict__ y,
                                                    const ushortT* __restrict__ xz,
                                                    ushortT* __restrict__ innerb)
{
  __shared__ float tile[64 * 65];
  int n0 = blockIdx.x * 64, d0 = blockIdx.y * 64;
  int tid = threadIdx.x;
  int c = tid & 63, rq = tid >> 6;
  #pragma unroll
  for (int r = 0; r < 16; r++) {
    int dd = rq + r * 4;
    float yv = bf2f(y[(size_t)(d0 + dd) * NCOLS + n0 + c]);
    float zv = bf2f(xz[(size_t)(DINNER + d0 + dd) * NCOLS + n0 + c]);
    float sv = zv / (1.f + __expf(-zv));
    tile[dd * 65 + c] = yv * sv;
  }
  __syncthreads();
  #pragma unroll
  for (int r = 0; r < 16; r++) {
    int nn = rq + r * 4;
    innerb[(size_t)(n0 + nn) * DINNER + d0 + c] = f2bf(tile[c * 65 + nn]);
  }
}

extern "C" void kernel_launch(void* const* d_in, const int* in_sizes, int n_in,
                              void* d_out, int out_size, void* d_ws, size_t ws_size,
                              hipStream_t stream)
{
  const float* x          = (const float*)d_in[0];
  const float* in_proj_w  = (const float*)d_in[1];
  const float* out_proj_w = (const float*)d_in[2];
  const float* conv_w     = (const float*)d_in[3];
  const float* conv_b     = (const float*)d_in[4];
  const float* xproj_w    = (const float*)d_in[5];
  const float* dt_w       = (const float*)d_in[6];
  const float* dt_b       = (const float*)d_in[7];
  const float* A_log      = (const float*)d_in[8];
  const float* Dp         = (const float*)d_in[9];
  const float* conv_w_b   = (const float*)d_in[10];
  const float* conv_b_b   = (const float*)d_in[11];
  const float* xproj_w_b  = (const float*)d_in[12];
  const float* dt_w_b     = (const float*)d_in[13];
  const float* dt_b_b     = (const float*)d_in[14];
  const float* A_log_b    = (const float*)d_in[15];
  const float* D_b        = (const float*)d_in[16];

  // --- workspace layout (peak 199.25 MiB), DTB in d_out ---
  char* ws = (char*)d_ws;
  ushortT* XZ   = (ushortT*)(ws + 0);
  ushortT* XC   = (ushortT*)(ws + 100663296);
  ushortT* YB   = (ushortT*)(ws + 150994944);
  float*   DTR  = (float*)  (ws + 201326592);
  float*   BT   = (float*)  (ws + 204472320);
  float*   CT   = (float*)  (ws + 205520896);
  ushortT* WOB  = (ushortT*)(ws + 206569472);
  ushortT* XB   = (ushortT*)(ws + 100663296);  // overlay on XC region (P0/P1 only)
  ushortT* WIB  = (ushortT*)(ws + 150994944);  // overlay on YB region (P0/P1 only)
  ushortT* DTB  = (ushortT*)d_out;             // 48 MiB exactly
  ushortT* INNER = XZ;                         // overlay on XZ x-half
  float* OUT = (float*)d_out;

  // bf16 conversions
  cvt_bf16_kernel<<<12288, 256, 0, stream>>>(x, XB, 3145728);
  cvt_bf16_kernel<<<2304, 256, 0, stream>>>(in_proj_w, WIB, 589824);
  cvt_bf16_kernel<<<1152, 256, 0, stream>>>(out_proj_w, WOB, 294912);

  // xz = in_proj_w @ x^T : (3072 x 16384), bf16 out
  gemm_nt<<<dim3(128, 24), 256, 0, stream>>>(WIB, XB, nullptr, XZ, E2, NCOLS, DIM, 1);

  // forward direction
  conv_silu_kernel<<<24576, 256, 0, stream>>>(XZ, conv_w, conv_b, XC, 0);
  xdbl_kernel<<<256, 256, 0, stream>>>(XC, xproj_w, DTR, BT, CT);
  dt_kernel<<<256, 256, 0, stream>>>(DTR, dt_w, dt_b, DTB);
  scan_kernel2<<<dim3(192, 4), 256, 0, stream>>>(XC, DTB, BT, CT, A_log, Dp, YB, 0);

  // reverse direction (reversed coords; y added at original positions)
  conv_silu_kernel<<<24576, 256, 0, stream>>>(XZ, conv_w_b, conv_b_b, XC, 1);
  xdbl_kernel<<<256, 256, 0, stream>>>(XC, xproj_w_b, DTR, BT, CT);
  dt_kernel<<<256, 256, 0, stream>>>(DTR, dt_w_b, dt_b_b, DTB);
  scan_kernel2<<<dim3(192, 4), 256, 0, stream>>>(XC, DTB, BT, CT, A_log_b, D_b, YB, 1);

  // inner = bf16( y * silu(z) ) transposed to (n, d)
  inner_kernel<<<dim3(256, 24), 256, 0, stream>>>(YB, XZ, INNER);

  // out = inner @ out_proj_w^T : (16384 x 768), fp32 out
  gemm_nt<<<dim3(6, 128), 256, 0, stream>>>(INNER, WOB, OUT, nullptr, NCOLS, DIM, DINNER, 0);
}

// Round 4
// 2963.573 us; speedup vs baseline: 1.1158x; 1.0693x over previous
//
#include <hip/hip_runtime.h>

#define L_SZ   4096
#define B_SZ   4
#define NCOLS  16384      // B_SZ * L_SZ
#define DIM    768
#define DINNER 1536
#define E2     3072       // 2*DINNER
#define DTRANK 48
#define DSTATE 16
#define NCHUNK 32
#define CLEN   128        // L_SZ / NCHUNK

typedef unsigned short ushortT;
typedef __attribute__((ext_vector_type(8))) short short8;
typedef __attribute__((ext_vector_type(4))) float floatx4;

__device__ __forceinline__ unsigned short f2bf(float f) {
  union { float f; unsigned u; } v; v.f = f;
  unsigned r = v.u + 0x7FFF + ((v.u >> 16) & 1);
  return (unsigned short)(r >> 16);
}
__device__ __forceinline__ float bf2f(unsigned short h) {
  union { unsigned u; float f; } v; v.u = ((unsigned)h) << 16;
  return v.f;
}

// ---------------- fp32 -> bf16 conversion ----------------
__global__ __launch_bounds__(256) void cvt_bf16_kernel(const float* __restrict__ in,
                                                       ushortT* __restrict__ out, int n4) {
  int i = blockIdx.x * 256 + threadIdx.x;
  if (i >= n4) return;
  float4 v = ((const float4*)in)[i];
  ushort4 o;
  o.x = f2bf(v.x); o.y = f2bf(v.y); o.z = f2bf(v.z); o.w = f2bf(v.w);
  ((ushort4*)out)[i] = o;
}

// ---------------- bf16 NT GEMM: C[m,n] = sum_k A[m,k]*B[n,k] ----------------
// Block swizzle: supergroups of G bn-tiles x all bm-tiles for L2 reuse (G | gridDim.x).
__global__ __launch_bounds__(256) void gemm_nt(const ushortT* __restrict__ A,
                                               const ushortT* __restrict__ Bm,
                                               float* __restrict__ Cf, ushortT* __restrict__ Cb,
                                               int M, int N, int K, int out_bf16, int G)
{
  __shared__ ushortT As[128 * 64];
  __shared__ ushortT Bs[128 * 64];
  int tid = threadIdx.x;
  int wave = tid >> 6, lane = tid & 63;
  int gid = blockIdx.y * gridDim.x + blockIdx.x;
  int per_sg = G * gridDim.y;
  int sg = gid / per_sg, r = gid % per_sg;
  int bm = r / G;
  int bn = sg * G + (r % G);
  const ushortT* Abase = A + (size_t)bm * 128 * K;
  const ushortT* Bbase = Bm + (size_t)bn * 128 * K;
  int lm = lane & 15, lq = lane >> 4;
  int wm = (wave >> 1) * 64, wn = (wave & 1) * 64;
  int rloc = lane >> 3;
  int c_st = (lane & 7) * 8;
  floatx4 acc[4][4] = {};

  for (int k0 = 0; k0 < K; k0 += 64) {
    __syncthreads();
    #pragma unroll
    for (int j = 0; j < 4; j++) {
      int t = wave * 4 + j;
      const ushortT* ga = Abase + (size_t)(t * 8 + rloc) * K + k0 + c_st;
      const ushortT* gb = Bbase + (size_t)(t * 8 + rloc) * K + k0 + c_st;
      __builtin_amdgcn_global_load_lds((const __attribute__((address_space(1))) void*)ga,
                                       (__attribute__((address_space(3))) void*)(As + t * 512),
                                       16, 0, 0);
      __builtin_amdgcn_global_load_lds((const __attribute__((address_space(1))) void*)gb,
                                       (__attribute__((address_space(3))) void*)(Bs + t * 512),
                                       16, 0, 0);
    }
    __syncthreads();
    #pragma unroll
    for (int ks = 0; ks < 2; ks++) {
      short8 af[4], bfv[4];
      #pragma unroll
      for (int i = 0; i < 4; i++)
        af[i] = *(const short8*)(As + (wm + i * 16 + lm) * 64 + ks * 32 + lq * 8);
      #pragma unroll
      for (int j2 = 0; j2 < 4; j2++)
        bfv[j2] = *(const short8*)(Bs + (wn + j2 * 16 + lm) * 64 + ks * 32 + lq * 8);
      #pragma unroll
      for (int i = 0; i < 4; i++)
        #pragma unroll
        for (int j2 = 0; j2 < 4; j2++)
          acc[i][j2] = __builtin_amdgcn_mfma_f32_16x16x32_bf16(af[i], bfv[j2], acc[i][j2], 0, 0, 0);
    }
  }
  #pragma unroll
  for (int i = 0; i < 4; i++) {
    #pragma unroll
    for (int j2 = 0; j2 < 4; j2++) {
      int mg = bm * 128 + wm + i * 16 + lq * 4;
      int ng = bn * 128 + wn + j2 * 16 + lm;
      #pragma unroll
      for (int q = 0; q < 4; q++) {
        size_t off = (size_t)(mg + q) * N + ng;
        if (out_bf16) Cb[off] = f2bf(acc[i][j2][q]);
        else          Cf[off] = acc[i][j2][q];
      }
    }
  }
}

// ---------------- causal depthwise conv(k=4) + silu, bf16 in/out ----------------
// Output stored CHUNK-INTERLEAVED within each (d,b) row of 4096:
//   perm(l) = ((l&127)>>2)*128 + (l>>7)*4 + (l&3)
// (reverse pass: same perm applied to reversed-sequence coordinate).
__global__ __launch_bounds__(256) void conv_silu_kernel(const ushortT* __restrict__ xz,
                                                        const float* __restrict__ w,
                                                        const float* __restrict__ bias,
                                                        ushortT* __restrict__ xc, int reverse)
{
  int idx = blockIdx.x * 256 + threadIdx.x;
  int l0 = (idx & 1023) << 2;
  int rb = idx >> 10;
  int b = rb & 3, d = rb >> 2;
  const ushortT* xin = xz + (size_t)d * NCOLS + b * L_SZ;
  float w0 = w[d * 4], w1 = w[d * 4 + 1], w2 = w[d * 4 + 2], w3 = w[d * 4 + 3];
  float bv = bias[d];
  float xv[8];
  float r0, r1, r2, r3;
  if (!reverse) {
    if (l0 >= 4) {
      ushort4 a = *(const ushort4*)(xin + l0 - 4);
      ushort4 c = *(const ushort4*)(xin + l0);
      xv[0]=bf2f(a.x); xv[1]=bf2f(a.y); xv[2]=bf2f(a.z); xv[3]=bf2f(a.w);
      xv[4]=bf2f(c.x); xv[5]=bf2f(c.y); xv[6]=bf2f(c.z); xv[7]=bf2f(c.w);
    } else {
      #pragma unroll
      for (int i = 0; i < 8; i++) { int p = l0 - 4 + i; xv[i] = (p >= 0) ? bf2f(xin[p]) : 0.f; }
    }
    r0 = bv + w0*xv[1] + w1*xv[2] + w2*xv[3] + w3*xv[4];
    r1 = bv + w0*xv[2] + w1*xv[3] + w2*xv[4] + w3*xv[5];
    r2 = bv + w0*xv[3] + w1*xv[4] + w2*xv[5] + w3*xv[6];
    r3 = bv + w0*xv[4] + w1*xv[5] + w2*xv[6] + w3*xv[7];
  } else {
    int base = 4092 - l0;
    if (l0 >= 4) {
      ushort4 a = *(const ushort4*)(xin + base);
      ushort4 c = *(const ushort4*)(xin + base + 4);
      xv[0]=bf2f(a.x); xv[1]=bf2f(a.y); xv[2]=bf2f(a.z); xv[3]=bf2f(a.w);
      xv[4]=bf2f(c.x); xv[5]=bf2f(c.y); xv[6]=bf2f(c.z); xv[7]=bf2f(c.w);
    } else {
      #pragma unroll
      for (int i = 0; i < 8; i++) { int p = base + i; xv[i] = (p <= 4095) ? bf2f(xin[p]) : 0.f; }
    }
    r0 = bv + w0*xv[6] + w1*xv[5] + w2*xv[4] + w3*xv[3];
    r1 = bv + w0*xv[5] + w1*xv[4] + w2*xv[3] + w3*xv[2];
    r2 = bv + w0*xv[4] + w1*xv[3] + w2*xv[2] + w3*xv[1];
    r3 = bv + w0*xv[3] + w1*xv[2] + w2*xv[1] + w3*xv[0];
  }
  ushort4 o;
  o.x = f2bf(r0 / (1.f + __expf(-r0)));
  o.y = f2bf(r1 / (1.f + __expf(-r1)));
  o.z = f2bf(r2 / (1.f + __expf(-r2)));
  o.w = f2bf(r3 / (1.f + __expf(-r3)));
  int cch = l0 >> 7, wsub = (l0 & 127) >> 2;   // perm: 4-aligned group
  *(ushort4*)(xc + (size_t)d * NCOLS + b * L_SZ + wsub * 128 + cch * 4) = o;
}

// ---------------- x_proj GEMM (fp32 vector): 80 x NCOLS from xc(bf16) ----------------
// Columns are permuted-indexed; outputs land at the same permuted columns (consistent).
__global__ __launch_bounds__(256) void xdbl_kernel(const ushortT* __restrict__ xc,
                                                   const float* __restrict__ W, // (80,1536)
                                                   float* __restrict__ dtr,
                                                   float* __restrict__ Bt,
                                                   float* __restrict__ Ct)
{
  __shared__ float xcs[32 * 68];
  __shared__ float Ws[80 * 32];
  int tid = threadIdx.x;
  int n0 = blockIdx.x * 64;
  int tm = tid >> 4, tn = tid & 15;
  float acc[5][4] = {};
  for (int k0 = 0; k0 < DINNER; k0 += 32) {
    __syncthreads();
    {
      int kk = tid >> 3, c8 = (tid & 7) * 8;
      const ushortT* src = xc + (size_t)(k0 + kk) * NCOLS + n0 + c8;
      ushort4 a = *(const ushort4*)src;
      ushort4 b = *(const ushort4*)(src + 4);
      float* dst = xcs + kk * 68 + c8;
      dst[0]=bf2f(a.x); dst[1]=bf2f(a.y); dst[2]=bf2f(a.z); dst[3]=bf2f(a.w);
      dst[4]=bf2f(b.x); dst[5]=bf2f(b.y); dst[6]=bf2f(b.z); dst[7]=bf2f(b.w);
    }
    for (int i = tid; i < 80 * 32; i += 256) {
      int m = i >> 5, kk = i & 31;
      Ws[i] = W[(size_t)m * DINNER + k0 + kk];
    }
    __syncthreads();
    #pragma unroll 8
    for (int kk = 0; kk < 32; kk++) {
      const float* xr = xcs + kk * 68 + tn * 4;
      float x0 = xr[0], x1 = xr[1], x2 = xr[2], x3 = xr[3];
      #pragma unroll
      for (int im = 0; im < 5; im++) {
        float wv = Ws[(tm * 5 + im) * 32 + kk];
        acc[im][0] += wv * x0; acc[im][1] += wv * x1;
        acc[im][2] += wv * x2; acc[im][3] += wv * x3;
      }
    }
  }
  #pragma unroll
  for (int im = 0; im < 5; im++) {
    int m = tm * 5 + im;
    #pragma unroll
    for (int j = 0; j < 4; j++) {
      int n = n0 + tn * 4 + j;
      float v = acc[im][j];
      if (m < 48)      dtr[(size_t)m * NCOLS + n] = v;
      else if (m < 64) Bt[(size_t)n * 16 + (m - 48)] = v;
      else             Ct[(size_t)n * 16 + (m - 64)] = v;
    }
  }
}

// ---------------- dt = softplus(dt_w @ dtr + bias), bf16 out (permuted cols) ----------------
__global__ __launch_bounds__(256) void dt_kernel(const float* __restrict__ dtr,
                                                 const float* __restrict__ W, // (1536,48)
                                                 const float* __restrict__ bias,
                                                 ushortT* __restrict__ dtb)
{
  __shared__ float s[48 * 64];
  int tid = threadIdx.x;
  int n0 = blockIdx.x * 64;
  for (int i = tid; i < 48 * 64; i += 256) {
    int r = i >> 6, c = i & 63;
    s[i] = dtr[(size_t)r * NCOLS + n0 + c];
  }
  __syncthreads();
  int n = tid & 63;
  for (int d = tid >> 6; d < DINNER; d += 4) {
    float accv = bias[d];
    const float* wr = W + (size_t)d * 48;
    #pragma unroll 12
    for (int r = 0; r < 48; r++) accv += wr[r] * s[r * 64 + n];
    float sp = (accv > 20.f) ? accv : log1pf(__expf(accv));
    dtb[(size_t)d * NCOLS + n0 + n] = f2bf(sp);
  }
}

// ---------------- chunked selective scan (two-pass, block-local combine) ----------------
// u/dt/B/C are chunk-interleaved: at step w, thread (dl,c) reads base + w*128 + c*4
// -> half-wave reads 256B contiguous. y is written at PLAIN coordinates.
// Block: 8 d-rows x 32 chunks; grid (DINNER/8, B_SZ).
__global__ __launch_bounds__(256) void scan_kernel2(const ushortT* __restrict__ u,
                                                    const ushortT* __restrict__ dt,
                                                    const float* __restrict__ Bt,
                                                    const float* __restrict__ Ct,
                                                    const float* __restrict__ A_log,
                                                    const float* __restrict__ Dp,
                                                    ushortT* __restrict__ y, int reverse)
{
  __shared__ float Ps[256 * 17];
  __shared__ float Hs[256 * 17];
  int tid = threadIdx.x;
  int c = tid & 31, dl = tid >> 5;
  int b = blockIdx.y;
  int d = blockIdx.x * 8 + dl;

  float Av2[16];
  #pragma unroll
  for (int n = 0; n < 16; n++)
    Av2[n] = -__expf(A_log[d * 16 + n]) * 1.442695040888963f;  // A * log2(e)
  float Dv = Dp[d];

  const ushortT* ur = u  + (size_t)d * NCOLS + b * L_SZ + c * 4;
  const ushortT* tr = dt + (size_t)d * NCOLS + b * L_SZ + c * 4;
  const float*   Bp = Bt + (size_t)b * L_SZ * 16;
  const float*   Cp = Ct + (size_t)b * L_SZ * 16;

  float h[16];
  float S = 0.f;
  #pragma unroll
  for (int n = 0; n < 16; n++) h[n] = 0.f;

  // ---- pass 1: chunk summaries ----
  for (int w = 0; w < 32; w++) {
    ushort4 u4 = *(const ushort4*)(ur + w * 128);
    ushort4 t4 = *(const ushort4*)(tr + w * 128);
    float uv[4] = { bf2f(u4.x), bf2f(u4.y), bf2f(u4.z), bf2f(u4.w) };
    float tv[4] = { bf2f(t4.x), bf2f(t4.y), bf2f(t4.z), bf2f(t4.w) };
    #pragma unroll
    for (int q = 0; q < 4; q++) {
      float dtu = tv[q] * uv[q];
      int pl = w * 128 + c * 4 + q;             // permuted column within (b) row
      const float4* bp4 = (const float4*)(Bp + pl * 16);
      float4 b0 = bp4[0], b1 = bp4[1], b2 = bp4[2], b3 = bp4[3];
      float Bf[16] = { b0.x,b0.y,b0.z,b0.w, b1.x,b1.y,b1.z,b1.w,
                       b2.x,b2.y,b2.z,b2.w, b3.x,b3.y,b3.z,b3.w };
      #pragma unroll
      for (int n = 0; n < 16; n++) {
        float e = exp2f(tv[q] * Av2[n]);
        h[n] = h[n] * e + Bf[n] * dtu;
      }
      S += tv[q];
    }
  }

  int base = tid * 17;
  #pragma unroll
  for (int n = 0; n < 16; n++) {
    Ps[base + n] = exp2f(Av2[n] * S);
    Hs[base + n] = h[n];
  }
  __syncthreads();

  // ---- combine: 128 threads, each (d-row, state) scans 32 chunks serially ----
  if (tid < 128) {
    int dl2 = tid >> 4, n2 = tid & 15;
    float hs = 0.f;
    for (int cc = 0; cc < NCHUNK; cc++) {
      int idx = (dl2 * NCHUNK + cc) * 17 + n2;
      float tmp = Hs[idx];
      Hs[idx] = hs;                   // h at chunk start
      hs = Ps[idx] * hs + tmp;        // h at chunk end
    }
  }
  __syncthreads();
  #pragma unroll
  for (int n = 0; n < 16; n++) h[n] = Hs[base + n];

  // ---- pass 2: recompute h from h_start, emit y at plain coords ----
  ushortT* yrow = y + (size_t)d * NCOLS + b * L_SZ;
  for (int w = 0; w < 32; w++) {
    ushort4 u4 = *(const ushort4*)(ur + w * 128);
    ushort4 t4 = *(const ushort4*)(tr + w * 128);
    float uv[4] = { bf2f(u4.x), bf2f(u4.y), bf2f(u4.z), bf2f(u4.w) };
    float tv[4] = { bf2f(t4.x), bf2f(t4.y), bf2f(t4.z), bf2f(t4.w) };
    float yo[4];
    #pragma unroll
    for (int q = 0; q < 4; q++) {
      float dtu = tv[q] * uv[q];
      int pl = w * 128 + c * 4 + q;
      const float4* bp4 = (const float4*)(Bp + pl * 16);
      const float4* cp4 = (const float4*)(Cp + pl * 16);
      float4 b0 = bp4[0], b1 = bp4[1], b2 = bp4[2], b3 = bp4[3];
      float4 c0 = cp4[0], c1 = cp4[1], c2 = cp4[2], c3 = cp4[3];
      float Bf[16] = { b0.x,b0.y,b0.z,b0.w, b1.x,b1.y,b1.z,b1.w,
                       b2.x,b2.y,b2.z,b2.w, b3.x,b3.y,b3.z,b3.w };
      float Cfv[16] = { c0.x,c0.y,c0.z,c0.w, c1.x,c1.y,c1.z,c1.w,
                        c2.x,c2.y,c2.z,c2.w, c3.x,c3.y,c3.z,c3.w };
      float acc = 0.f;
      #pragma unroll
      for (int n = 0; n < 16; n++) {
        float e = exp2f(tv[q] * Av2[n]);
        h[n] = h[n] * e + Bf[n] * dtu;
        acc += h[n] * Cfv[n];
      }
      yo[q] = acc + Dv * uv[q];
    }
    if (!reverse) {
      ushort4 o;
      o.x = f2bf(yo[0]); o.y = f2bf(yo[1]); o.z = f2bf(yo[2]); o.w = f2bf(yo[3]);
      *(ushort4*)(yrow + c * CLEN + w * 4) = o;
    } else {
      ushort4* dst = (ushort4*)(yrow + (4092 - c * CLEN - w * 4));  // orig pos 4095-l
      ushort4 old = *dst;
      ushort4 o;
      o.x = f2bf(bf2f(old.x) + yo[3]);
      o.y = f2bf(bf2f(old.y) + yo[2]);
      o.z = f2bf(bf2f(old.z) + yo[1]);
      o.w = f2bf(bf2f(old.w) + yo[0]);
      *dst = o;
    }
  }
}

// ---------------- inner = bf16( y * silu(z) ), transposed to (n, d) ----------------
__global__ __launch_bounds__(256) void inner_kernel(const ushortT* __restrict__ y,
                                                    const ushortT* __restrict__ xz,
                                                    ushortT* __restrict__ innerb)
{
  __shared__ float tile[64 * 65];
  int n0 = blockIdx.x * 64, d0 = blockIdx.y * 64;
  int tid = threadIdx.x;
  int c = tid & 63, rq = tid >> 6;
  #pragma unroll
  for (int r = 0; r < 16; r++) {
    int dd = rq + r * 4;
    float yv = bf2f(y[(size_t)(d0 + dd) * NCOLS + n0 + c]);
    float zv = bf2f(xz[(size_t)(DINNER + d0 + dd) * NCOLS + n0 + c]);
    float sv = zv / (1.f + __expf(-zv));
    tile[dd * 65 + c] = yv * sv;
  }
  __syncthreads();
  #pragma unroll
  for (int r = 0; r < 16; r++) {
    int nn = rq + r * 4;
    innerb[(size_t)(n0 + nn) * DINNER + d0 + c] = f2bf(tile[c * 65 + nn]);
  }
}

extern "C" void kernel_launch(void* const* d_in, const int* in_sizes, int n_in,
                              void* d_out, int out_size, void* d_ws, size_t ws_size,
                              hipStream_t stream)
{
  const float* x          = (const float*)d_in[0];
  const float* in_proj_w  = (const float*)d_in[1];
  const float* out_proj_w = (const float*)d_in[2];
  const float* conv_w     = (const float*)d_in[3];
  const float* conv_b     = (const float*)d_in[4];
  const float* xproj_w    = (const float*)d_in[5];
  const float* dt_w       = (const float*)d_in[6];
  const float* dt_b       = (const float*)d_in[7];
  const float* A_log      = (const float*)d_in[8];
  const float* Dp         = (const float*)d_in[9];
  const float* conv_w_b   = (const float*)d_in[10];
  const float* conv_b_b   = (const float*)d_in[11];
  const float* xproj_w_b  = (const float*)d_in[12];
  const float* dt_w_b     = (const float*)d_in[13];
  const float* dt_b_b     = (const float*)d_in[14];
  const float* A_log_b    = (const float*)d_in[15];
  const float* D_b        = (const float*)d_in[16];

  // --- workspace layout (peak 199.25 MiB), DTB in d_out ---
  char* ws = (char*)d_ws;
  ushortT* XZ   = (ushortT*)(ws + 0);
  ushortT* XC   = (ushortT*)(ws + 100663296);
  ushortT* YB   = (ushortT*)(ws + 150994944);
  float*   DTR  = (float*)  (ws + 201326592);
  float*   BT   = (float*)  (ws + 204472320);
  float*   CT   = (float*)  (ws + 205520896);
  ushortT* WOB  = (ushortT*)(ws + 206569472);
  ushortT* XB   = (ushortT*)(ws + 100663296);  // overlay on XC region (P0/P1 only)
  ushortT* WIB  = (ushortT*)(ws + 150994944);  // overlay on YB region (P0/P1 only)
  ushortT* DTB  = (ushortT*)d_out;             // 48 MiB exactly
  ushortT* INNER = XZ;                         // overlay on XZ x-half
  float* OUT = (float*)d_out;

  // bf16 conversions
  cvt_bf16_kernel<<<12288, 256, 0, stream>>>(x, XB, 3145728);
  cvt_bf16_kernel<<<2304, 256, 0, stream>>>(in_proj_w, WIB, 589824);
  cvt_bf16_kernel<<<1152, 256, 0, stream>>>(out_proj_w, WOB, 294912);

  // xz = in_proj_w @ x^T : (3072 x 16384), bf16 out; G=16 swizzle for L2 reuse
  gemm_nt<<<dim3(128, 24), 256, 0, stream>>>(WIB, XB, nullptr, XZ, E2, NCOLS, DIM, 1, 16);

  // forward direction
  conv_silu_kernel<<<24576, 256, 0, stream>>>(XZ, conv_w, conv_b, XC, 0);
  xdbl_kernel<<<256, 256, 0, stream>>>(XC, xproj_w, DTR, BT, CT);
  dt_kernel<<<256, 256, 0, stream>>>(DTR, dt_w, dt_b, DTB);
  scan_kernel2<<<dim3(192, 4), 256, 0, stream>>>(XC, DTB, BT, CT, A_log, Dp, YB, 0);

  // reverse direction (reversed coords; y added at original positions)
  conv_silu_kernel<<<24576, 256, 0, stream>>>(XZ, conv_w_b, conv_b_b, XC, 1);
  xdbl_kernel<<<256, 256, 0, stream>>>(XC, xproj_w_b, DTR, BT, CT);
  dt_kernel<<<256, 256, 0, stream>>>(DTR, dt_w_b, dt_b_b, DTB);
  scan_kernel2<<<dim3(192, 4), 256, 0, stream>>>(XC, DTB, BT, CT, A_log_b, D_b, YB, 1);

  // inner = bf16( y * silu(z) ) transposed to (n, d)
  inner_kernel<<<dim3(256, 24), 256, 0, stream>>>(YB, XZ, INNER);

  // out = inner @ out_proj_w^T : (16384 x 768), fp32 out
  gemm_nt<<<dim3(6, 128), 256, 0, stream>>>(INNER, WOB, OUT, nullptr, NCOLS, DIM, DINNER, 0, 6);
}

// Round 5
// 2706.224 us; speedup vs baseline: 1.2219x; 1.0951x over previous
//
#include <hip/hip_runtime.h>

#define L_SZ   4096
#define B_SZ   4
#define NCOLS  16384      // B_SZ * L_SZ
#define DIM    768
#define DINNER 1536
#define E2     3072       // 2*DINNER
#define DTRANK 48
#define DSTATE 16
#define NCHUNK 64
#define CLEN   64         // L_SZ / NCHUNK

// perm within each (d,b) 4096-row: l = c*64 + w*4 + q  ->  off = w*256 + c*4 + q
// (c = chunk 0..63, w = 0..15, q = 0..3)

typedef unsigned short ushortT;
typedef __attribute__((ext_vector_type(8))) short short8;
typedef __attribute__((ext_vector_type(4))) float floatx4;

__device__ __forceinline__ unsigned short f2bf(float f) {
  union { float f; unsigned u; } v; v.f = f;
  unsigned r = v.u + 0x7FFF + ((v.u >> 16) & 1);
  return (unsigned short)(r >> 16);
}
__device__ __forceinline__ float bf2f(unsigned short h) {
  union { unsigned u; float f; } v; v.u = ((unsigned)h) << 16;
  return v.f;
}

// ---------------- fp32 -> bf16 conversion ----------------
__global__ __launch_bounds__(256) void cvt_bf16_kernel(const float* __restrict__ in,
                                                       ushortT* __restrict__ out, int n4) {
  int i = blockIdx.x * 256 + threadIdx.x;
  if (i >= n4) return;
  float4 v = ((const float4*)in)[i];
  ushort4 o;
  o.x = f2bf(v.x); o.y = f2bf(v.y); o.z = f2bf(v.z); o.w = f2bf(v.w);
  ((ushort4*)out)[i] = o;
}

// ---------------- bf16 NT GEMM: C[m,n] = sum_k A[m,k]*B[n,k] ----------------
__global__ __launch_bounds__(256) void gemm_nt(const ushortT* __restrict__ A,
                                               const ushortT* __restrict__ Bm,
                                               float* __restrict__ Cf, ushortT* __restrict__ Cb,
                                               int M, int N, int K, int out_bf16, int G)
{
  __shared__ ushortT As[128 * 64];
  __shared__ ushortT Bs[128 * 64];
  int tid = threadIdx.x;
  int wave = tid >> 6, lane = tid & 63;
  int gid = blockIdx.y * gridDim.x + blockIdx.x;
  int per_sg = G * gridDim.y;
  int sg = gid / per_sg, r = gid % per_sg;
  int bm = r / G;
  int bn = sg * G + (r % G);
  const ushortT* Abase = A + (size_t)bm * 128 * K;
  const ushortT* Bbase = Bm + (size_t)bn * 128 * K;
  int lm = lane & 15, lq = lane >> 4;
  int wm = (wave >> 1) * 64, wn = (wave & 1) * 64;
  int rloc = lane >> 3;
  int c_st = (lane & 7) * 8;
  floatx4 acc[4][4] = {};

  for (int k0 = 0; k0 < K; k0 += 64) {
    __syncthreads();
    #pragma unroll
    for (int j = 0; j < 4; j++) {
      int t = wave * 4 + j;
      const ushortT* ga = Abase + (size_t)(t * 8 + rloc) * K + k0 + c_st;
      const ushortT* gb = Bbase + (size_t)(t * 8 + rloc) * K + k0 + c_st;
      __builtin_amdgcn_global_load_lds((const __attribute__((address_space(1))) void*)ga,
                                       (__attribute__((address_space(3))) void*)(As + t * 512),
                                       16, 0, 0);
      __builtin_amdgcn_global_load_lds((const __attribute__((address_space(1))) void*)gb,
                                       (__attribute__((address_space(3))) void*)(Bs + t * 512),
                                       16, 0, 0);
    }
    __syncthreads();
    #pragma unroll
    for (int ks = 0; ks < 2; ks++) {
      short8 af[4], bfv[4];
      #pragma unroll
      for (int i = 0; i < 4; i++)
        af[i] = *(const short8*)(As + (wm + i * 16 + lm) * 64 + ks * 32 + lq * 8);
      #pragma unroll
      for (int j2 = 0; j2 < 4; j2++)
        bfv[j2] = *(const short8*)(Bs + (wn + j2 * 16 + lm) * 64 + ks * 32 + lq * 8);
      #pragma unroll
      for (int i = 0; i < 4; i++)
        #pragma unroll
        for (int j2 = 0; j2 < 4; j2++)
          acc[i][j2] = __builtin_amdgcn_mfma_f32_16x16x32_bf16(af[i], bfv[j2], acc[i][j2], 0, 0, 0);
    }
  }
  #pragma unroll
  for (int i = 0; i < 4; i++) {
    #pragma unroll
    for (int j2 = 0; j2 < 4; j2++) {
      int mg = bm * 128 + wm + i * 16 + lq * 4;
      int ng = bn * 128 + wn + j2 * 16 + lm;
      #pragma unroll
      for (int q = 0; q < 4; q++) {
        size_t off = (size_t)(mg + q) * N + ng;
        if (out_bf16) Cb[off] = f2bf(acc[i][j2][q]);
        else          Cf[off] = acc[i][j2][q];
      }
    }
  }
}

// ---------------- causal depthwise conv(k=4) + silu, bf16 in/out ----------------
// Thread owns permuted-contiguous ushort4 at p4 = w*64+c: plain l0 = c*64 + w*4.
// Writes are fully coalesced in permuted space.
__global__ __launch_bounds__(256) void conv_silu_kernel(const ushortT* __restrict__ xz,
                                                        const float* __restrict__ w,
                                                        const float* __restrict__ bias,
                                                        ushortT* __restrict__ xc, int reverse)
{
  int idx = blockIdx.x * 256 + threadIdx.x;
  int p4 = idx & 1023;
  int rb = idx >> 10;
  int b = rb & 3, d = rb >> 2;
  int wq = p4 >> 6, c = p4 & 63;
  int l0 = c * 64 + wq * 4;                    // plain (or reversed-seq) position
  const ushortT* xin = xz + (size_t)d * NCOLS + b * L_SZ;
  float w0 = w[d * 4], w1 = w[d * 4 + 1], w2 = w[d * 4 + 2], w3 = w[d * 4 + 3];
  float bv = bias[d];
  float xv[8];
  float r0, r1, r2, r3;
  if (!reverse) {
    if (l0 >= 4) {
      ushort4 a = *(const ushort4*)(xin + l0 - 4);
      ushort4 cc = *(const ushort4*)(xin + l0);
      xv[0]=bf2f(a.x); xv[1]=bf2f(a.y); xv[2]=bf2f(a.z); xv[3]=bf2f(a.w);
      xv[4]=bf2f(cc.x); xv[5]=bf2f(cc.y); xv[6]=bf2f(cc.z); xv[7]=bf2f(cc.w);
    } else {
      #pragma unroll
      for (int i = 0; i < 8; i++) { int p = l0 - 4 + i; xv[i] = (p >= 0) ? bf2f(xin[p]) : 0.f; }
    }
    r0 = bv + w0*xv[1] + w1*xv[2] + w2*xv[3] + w3*xv[4];
    r1 = bv + w0*xv[2] + w1*xv[3] + w2*xv[4] + w3*xv[5];
    r2 = bv + w0*xv[3] + w1*xv[4] + w2*xv[5] + w3*xv[6];
    r3 = bv + w0*xv[4] + w1*xv[5] + w2*xv[6] + w3*xv[7];
  } else {
    int base = 4092 - l0;
    if (l0 >= 4) {
      ushort4 a = *(const ushort4*)(xin + base);
      ushort4 cc = *(const ushort4*)(xin + base + 4);
      xv[0]=bf2f(a.x); xv[1]=bf2f(a.y); xv[2]=bf2f(a.z); xv[3]=bf2f(a.w);
      xv[4]=bf2f(cc.x); xv[5]=bf2f(cc.y); xv[6]=bf2f(cc.z); xv[7]=bf2f(cc.w);
    } else {
      #pragma unroll
      for (int i = 0; i < 8; i++) { int p = base + i; xv[i] = (p <= 4095) ? bf2f(xin[p]) : 0.f; }
    }
    r0 = bv + w0*xv[6] + w1*xv[5] + w2*xv[4] + w3*xv[3];
    r1 = bv + w0*xv[5] + w1*xv[4] + w2*xv[3] + w3*xv[2];
    r2 = bv + w0*xv[4] + w1*xv[3] + w2*xv[2] + w3*xv[1];
    r3 = bv + w0*xv[3] + w1*xv[2] + w2*xv[1] + w3*xv[0];
  }
  ushort4 o;
  o.x = f2bf(r0 / (1.f + __expf(-r0)));
  o.y = f2bf(r1 / (1.f + __expf(-r1)));
  o.z = f2bf(r2 / (1.f + __expf(-r2)));
  o.w = f2bf(r3 / (1.f + __expf(-r3)));
  *(ushort4*)(xc + (size_t)d * NCOLS + b * L_SZ + p4 * 4) = o;
}

// ---------------- x_proj GEMM (fp32 vector): 80 x NCOLS from xc(bf16) ----------------
// Columns permuted-indexed; outputs land at the same permuted columns (consistent).
__global__ __launch_bounds__(256) void xdbl_kernel(const ushortT* __restrict__ xc,
                                                   const float* __restrict__ W, // (80,1536)
                                                   float* __restrict__ dtr,
                                                   float* __restrict__ Bt,
                                                   float* __restrict__ Ct)
{
  __shared__ float xcs[32 * 68];
  __shared__ float Ws[80 * 32];
  int tid = threadIdx.x;
  int n0 = blockIdx.x * 64;
  int tm = tid >> 4, tn = tid & 15;
  float acc[5][4] = {};
  for (int k0 = 0; k0 < DINNER; k0 += 32) {
    __syncthreads();
    {
      int kk = tid >> 3, c8 = (tid & 7) * 8;
      const ushortT* src = xc + (size_t)(k0 + kk) * NCOLS + n0 + c8;
      ushort4 a = *(const ushort4*)src;
      ushort4 b = *(const ushort4*)(src + 4);
      float* dst = xcs + kk * 68 + c8;
      dst[0]=bf2f(a.x); dst[1]=bf2f(a.y); dst[2]=bf2f(a.z); dst[3]=bf2f(a.w);
      dst[4]=bf2f(b.x); dst[5]=bf2f(b.y); dst[6]=bf2f(b.z); dst[7]=bf2f(b.w);
    }
    for (int i = tid; i < 80 * 32; i += 256) {
      int m = i >> 5, kk = i & 31;
      Ws[i] = W[(size_t)m * DINNER + k0 + kk];
    }
    __syncthreads();
    #pragma unroll 8
    for (int kk = 0; kk < 32; kk++) {
      const float* xr = xcs + kk * 68 + tn * 4;
      float x0 = xr[0], x1 = xr[1], x2 = xr[2], x3 = xr[3];
      #pragma unroll
      for (int im = 0; im < 5; im++) {
        float wv = Ws[(tm * 5 + im) * 32 + kk];
        acc[im][0] += wv * x0; acc[im][1] += wv * x1;
        acc[im][2] += wv * x2; acc[im][3] += wv * x3;
      }
    }
  }
  #pragma unroll
  for (int im = 0; im < 5; im++) {
    int m = tm * 5 + im;
    #pragma unroll
    for (int j = 0; j < 4; j++) {
      int n = n0 + tn * 4 + j;
      float v = acc[im][j];
      if (m < 48)      dtr[(size_t)m * NCOLS + n] = v;
      else if (m < 64) Bt[(size_t)n * 16 + (m - 48)] = v;
      else             Ct[(size_t)n * 16 + (m - 64)] = v;
    }
  }
}

// ---------------- dt = softplus(dt_w @ dtr + bias), bf16 out (permuted cols) ----------------
__global__ __launch_bounds__(256) void dt_kernel(const float* __restrict__ dtr,
                                                 const float* __restrict__ W, // (1536,48)
                                                 const float* __restrict__ bias,
                                                 ushortT* __restrict__ dtb)
{
  __shared__ float s[48 * 64];
  int tid = threadIdx.x;
  int n0 = blockIdx.x * 64;
  for (int i = tid; i < 48 * 64; i += 256) {
    int r = i >> 6, c = i & 63;
    s[i] = dtr[(size_t)r * NCOLS + n0 + c];
  }
  __syncthreads();
  int n = tid & 63;
  for (int d = tid >> 6; d < DINNER; d += 4) {
    float accv = bias[d];
    const float* wr = W + (size_t)d * 48;
    #pragma unroll 12
    for (int r = 0; r < 48; r++) accv += wr[r] * s[r * 64 + n];
    float sp = (accv > 20.f) ? accv : log1pf(__expf(accv));
    dtb[(size_t)d * NCOLS + n0 + n] = f2bf(sp);
  }
}

// ---------------- chunked selective scan v3 ----------------
// Block 256 = 2 d-rows x 64 chunks x 2 state-halves (8 states/thread).
// CLEN=64. u/dt/B/C and y all chunk-interleaved (perm above).
// Grid (DINNER/2, B_SZ) = (768,4) -> 12 blocks/CU.
__global__ __launch_bounds__(256) void scan_kernel3(const ushortT* __restrict__ u,
                                                    const ushortT* __restrict__ dt,
                                                    const float* __restrict__ Bt,
                                                    const float* __restrict__ Ct,
                                                    const float* __restrict__ A_log,
                                                    const float* __restrict__ Dp,
                                                    ushortT* __restrict__ y, int reverse)
{
  __shared__ float Ps[32 * 65];
  __shared__ float Hs[32 * 65];
  int tid = threadIdx.x;
  int hf = tid & 1;                  // state half
  int c  = (tid >> 1) & 63;          // chunk
  int dl = tid >> 7;                 // d-row within block (0,1)
  int b = blockIdx.y;
  int d = blockIdx.x * 2 + dl;
  int ns0 = hf * 8;

  float Av2[8];
  #pragma unroll
  for (int n = 0; n < 8; n++)
    Av2[n] = -__expf(A_log[d * 16 + ns0 + n]) * 1.442695040888963f;  // A*log2(e)
  float Dv = Dp[d];

  const ushortT* ur = u  + (size_t)d * NCOLS + b * L_SZ + c * 4;
  const ushortT* tr = dt + (size_t)d * NCOLS + b * L_SZ + c * 4;
  const float*   Bp = Bt + (size_t)b * L_SZ * 16 + ns0;
  const float*   Cp = Ct + (size_t)b * L_SZ * 16 + ns0;

  float h[8];
  float S = 0.f;
  #pragma unroll
  for (int n = 0; n < 8; n++) h[n] = 0.f;

  // ---- pass 1: chunk summaries ----
  for (int w = 0; w < 16; w++) {
    ushort4 u4 = *(const ushort4*)(ur + w * 256);
    ushort4 t4 = *(const ushort4*)(tr + w * 256);
    float uv[4] = { bf2f(u4.x), bf2f(u4.y), bf2f(u4.z), bf2f(u4.w) };
    float tv[4] = { bf2f(t4.x), bf2f(t4.y), bf2f(t4.z), bf2f(t4.w) };
    #pragma unroll
    for (int q = 0; q < 4; q++) {
      float dtu = tv[q] * uv[q];
      int pl = w * 256 + c * 4 + q;
      const float4* bp4 = (const float4*)(Bp + pl * 16);
      float4 b0 = bp4[0], b1 = bp4[1];
      float Bf[8] = { b0.x,b0.y,b0.z,b0.w, b1.x,b1.y,b1.z,b1.w };
      #pragma unroll
      for (int n = 0; n < 8; n++) {
        float e = exp2f(tv[q] * Av2[n]);
        h[n] = h[n] * e + Bf[n] * dtu;
      }
      S += tv[q];
    }
  }

  #pragma unroll
  for (int n = 0; n < 8; n++) {
    int row = dl * 16 + ns0 + n;
    Ps[row * 65 + c] = exp2f(Av2[n] * S);
    Hs[row * 65 + c] = h[n];
  }
  __syncthreads();

  // ---- combine: 32 threads = (d-row, state); serial over 64 chunks ----
  if (tid < 32) {
    int row = tid;
    float hs = 0.f;
    for (int cc = 0; cc < NCHUNK; cc++) {
      int idx = row * 65 + cc;
      float tmp = Hs[idx];
      Hs[idx] = hs;                   // h at chunk start
      hs = Ps[idx] * hs + tmp;        // h at chunk end
    }
  }
  __syncthreads();
  #pragma unroll
  for (int n = 0; n < 8; n++) h[n] = Hs[(dl * 16 + ns0 + n) * 65 + c];

  // ---- pass 2: recompute h from h_start, emit y in PERMUTED layout ----
  ushortT* yrow = y + (size_t)d * NCOLS + b * L_SZ;
  for (int w = 0; w < 16; w++) {
    ushort4 u4 = *(const ushort4*)(ur + w * 256);
    ushort4 t4 = *(const ushort4*)(tr + w * 256);
    float uv[4] = { bf2f(u4.x), bf2f(u4.y), bf2f(u4.z), bf2f(u4.w) };
    float tv[4] = { bf2f(t4.x), bf2f(t4.y), bf2f(t4.z), bf2f(t4.w) };
    float yo[4];
    #pragma unroll
    for (int q = 0; q < 4; q++) {
      float dtu = tv[q] * uv[q];
      int pl = w * 256 + c * 4 + q;
      const float4* bp4 = (const float4*)(Bp + pl * 16);
      const float4* cp4 = (const float4*)(Cp + pl * 16);
      float4 b0 = bp4[0], b1 = bp4[1];
      float4 c0 = cp4[0], c1 = cp4[1];
      float Bf[8] = { b0.x,b0.y,b0.z,b0.w, b1.x,b1.y,b1.z,b1.w };
      float Cv[8] = { c0.x,c0.y,c0.z,c0.w, c1.x,c1.y,c1.z,c1.w };
      float acc = 0.f;
      #pragma unroll
      for (int n = 0; n < 8; n++) {
        float e = exp2f(tv[q] * Av2[n]);
        h[n] = h[n] * e + Bf[n] * dtu;
        acc += h[n] * Cv[n];
      }
      acc += __shfl_xor(acc, 1);       // combine the two state-halves
      yo[q] = acc + Dv * uv[q];
    }
    if (hf == 0) {
      if (!reverse) {
        ushort4 o;
        o.x = f2bf(yo[0]); o.y = f2bf(yo[1]); o.z = f2bf(yo[2]); o.w = f2bf(yo[3]);
        *(ushort4*)(yrow + w * 256 + c * 4) = o;
      } else {
        // plain l = 4095 - lrev maps to permuted (15-w)*256 + (63-c)*4 + (3-q)
        ushort4* dst = (ushort4*)(yrow + (15 - w) * 256 + (63 - c) * 4);
        ushort4 old = *dst;
        ushort4 o;
        o.x = f2bf(bf2f(old.x) + yo[3]);
        o.y = f2bf(bf2f(old.y) + yo[2]);
        o.z = f2bf(bf2f(old.z) + yo[1]);
        o.w = f2bf(bf2f(old.w) + yo[0]);
        *dst = o;
      }
    }
  }
}

// ---------------- inner = bf16( y * silu(z) ), transposed to (n, d) ----------------
// y is in permuted layout; z (xz) and output are plain.
__global__ __launch_bounds__(256) void inner_kernel(const ushortT* __restrict__ y,
                                                    const ushortT* __restrict__ xz,
                                                    ushortT* __restrict__ innerb)
{
  __shared__ float tile[64 * 65];
  int n0 = blockIdx.x * 64, d0 = blockIdx.y * 64;
  int tid = threadIdx.x;
  int c = tid & 63, rq = tid >> 6;
  int bseg = n0 & ~4095;                        // b * L_SZ
  int cch = (n0 & 4095) >> 6;                   // chunk (fixed for this tile)
  int poff = bseg + cch * 4 + (c >> 2) * 256 + (c & 3);  // permuted column of plain n0+c
  #pragma unroll
  for (int r = 0; r < 16; r++) {
    int dd = rq + r * 4;
    float yv = bf2f(y[(size_t)(d0 + dd) * NCOLS + poff]);
    float zv = bf2f(xz[(size_t)(DINNER + d0 + dd) * NCOLS + n0 + c]);
    float sv = zv / (1.f + __expf(-zv));
    tile[dd * 65 + c] = yv * sv;
  }
  __syncthreads();
  #pragma unroll
  for (int r = 0; r < 16; r++) {
    int nn = rq + r * 4;
    innerb[(size_t)(n0 + nn) * DINNER + d0 + c] = f2bf(tile[c * 65 + nn]);
  }
}

extern "C" void kernel_launch(void* const* d_in, const int* in_sizes, int n_in,
                              void* d_out, int out_size, void* d_ws, size_t ws_size,
                              hipStream_t stream)
{
  const float* x          = (const float*)d_in[0];
  const float* in_proj_w  = (const float*)d_in[1];
  const float* out_proj_w = (const float*)d_in[2];
  const float* conv_w     = (const float*)d_in[3];
  const float* conv_b     = (const float*)d_in[4];
  const float* xproj_w    = (const float*)d_in[5];
  const float* dt_w       = (const float*)d_in[6];
  const float* dt_b       = (const float*)d_in[7];
  const float* A_log      = (const float*)d_in[8];
  const float* Dp         = (const float*)d_in[9];
  const float* conv_w_b   = (const float*)d_in[10];
  const float* conv_b_b   = (const float*)d_in[11];
  const float* xproj_w_b  = (const float*)d_in[12];
  const float* dt_w_b     = (const float*)d_in[13];
  const float* dt_b_b     = (const float*)d_in[14];
  const float* A_log_b    = (const float*)d_in[15];
  const float* D_b        = (const float*)d_in[16];

  // --- workspace layout (peak 199.25 MiB), DTB in d_out ---
  char* ws = (char*)d_ws;
  ushortT* XZ   = (ushortT*)(ws + 0);
  ushortT* XC   = (ushortT*)(ws + 100663296);
  ushortT* YB   = (ushortT*)(ws + 150994944);
  float*   DTR  = (float*)  (ws + 201326592);
  float*   BT   = (float*)  (ws + 204472320);
  float*   CT   = (float*)  (ws + 205520896);
  ushortT* WOB  = (ushortT*)(ws + 206569472);
  ushortT* XB   = (ushortT*)(ws + 100663296);  // overlay on XC region (P0/P1 only)
  ushortT* WIB  = (ushortT*)(ws + 150994944);  // overlay on YB region (P0/P1 only)
  ushortT* DTB  = (ushortT*)d_out;             // 48 MiB exactly
  ushortT* INNER = XZ;                         // overlay on XZ x-half
  float* OUT = (float*)d_out;

  // bf16 conversions
  cvt_bf16_kernel<<<12288, 256, 0, stream>>>(x, XB, 3145728);
  cvt_bf16_kernel<<<2304, 256, 0, stream>>>(in_proj_w, WIB, 589824);
  cvt_bf16_kernel<<<1152, 256, 0, stream>>>(out_proj_w, WOB, 294912);

  // xz = in_proj_w @ x^T : (3072 x 16384), bf16 out; G=16 swizzle for L2 reuse
  gemm_nt<<<dim3(128, 24), 256, 0, stream>>>(WIB, XB, nullptr, XZ, E2, NCOLS, DIM, 1, 16);

  // forward direction
  conv_silu_kernel<<<24576, 256, 0, stream>>>(XZ, conv_w, conv_b, XC, 0);
  xdbl_kernel<<<256, 256, 0, stream>>>(XC, xproj_w, DTR, BT, CT);
  dt_kernel<<<256, 256, 0, stream>>>(DTR, dt_w, dt_b, DTB);
  scan_kernel3<<<dim3(768, 4), 256, 0, stream>>>(XC, DTB, BT, CT, A_log, Dp, YB, 0);

  // reverse direction (reversed coords; y added at original positions, permuted layout)
  conv_silu_kernel<<<24576, 256, 0, stream>>>(XZ, conv_w_b, conv_b_b, XC, 1);
  xdbl_kernel<<<256, 256, 0, stream>>>(XC, xproj_w_b, DTR, BT, CT);
  dt_kernel<<<256, 256, 0, stream>>>(DTR, dt_w_b, dt_b_b, DTB);
  scan_kernel3<<<dim3(768, 4), 256, 0, stream>>>(XC, DTB, BT, CT, A_log_b, D_b, YB, 1);

  // inner = bf16( y * silu(z) ) transposed to (n, d); un-permutes y
  inner_kernel<<<dim3(256, 24), 256, 0, stream>>>(YB, XZ, INNER);

  // out = inner @ out_proj_w^T : (16384 x 768), fp32 out
  gemm_nt<<<dim3(6, 128), 256, 0, stream>>>(INNER, WOB, OUT, nullptr, NCOLS, DIM, DINNER, 0, 6);
}

// Round 6
// 2024.443 us; speedup vs baseline: 1.6334x; 1.3368x over previous
//
#include <hip/hip_runtime.h>

#define L_SZ   4096
#define B_SZ   4
#define NCOLS  16384      // B_SZ * L_SZ
#define DIM    768
#define DINNER 1536
#define E2     3072       // 2*DINNER
#define DTRANK 48
#define DSTATE 16
#define NCHUNK 64
#define CLEN   64         // L_SZ / NCHUNK

// perm within each (d,b) 4096-row: l = c*64 + w*4 + q  ->  off = w*256 + c*4 + q
// (c = chunk 0..63, w = 0..15, q = 0..3)

typedef unsigned short ushortT;
typedef __attribute__((ext_vector_type(8))) short short8;
typedef __attribute__((ext_vector_type(4))) float floatx4;

__device__ __forceinline__ unsigned short f2bf(float f) {
  union { float f; unsigned u; } v; v.f = f;
  unsigned r = v.u + 0x7FFF + ((v.u >> 16) & 1);
  return (unsigned short)(r >> 16);
}
__device__ __forceinline__ float bf2f(unsigned short h) {
  union { unsigned u; float f; } v; v.u = ((unsigned)h) << 16;
  return v.f;
}

// ---------------- fp32 -> bf16 conversion ----------------
__global__ __launch_bounds__(256) void cvt_bf16_kernel(const float* __restrict__ in,
                                                       ushortT* __restrict__ out, int n4) {
  int i = blockIdx.x * 256 + threadIdx.x;
  if (i >= n4) return;
  float4 v = ((const float4*)in)[i];
  ushort4 o;
  o.x = f2bf(v.x); o.y = f2bf(v.y); o.z = f2bf(v.z); o.w = f2bf(v.w);
  ((ushort4*)out)[i] = o;
}

// ---------------- bf16 NT GEMM: C[m,n] = sum_k A[m,k]*B[n,k] ----------------
__global__ __launch_bounds__(256) void gemm_nt(const ushortT* __restrict__ A,
                                               const ushortT* __restrict__ Bm,
                                               float* __restrict__ Cf, ushortT* __restrict__ Cb,
                                               int M, int N, int K, int out_bf16, int G)
{
  __shared__ ushortT As[128 * 64];
  __shared__ ushortT Bs[128 * 64];
  int tid = threadIdx.x;
  int wave = tid >> 6, lane = tid & 63;
  int gid = blockIdx.y * gridDim.x + blockIdx.x;
  int per_sg = G * gridDim.y;
  int sg = gid / per_sg, r = gid % per_sg;
  int bm = r / G;
  int bn = sg * G + (r % G);
  const ushortT* Abase = A + (size_t)bm * 128 * K;
  const ushortT* Bbase = Bm + (size_t)bn * 128 * K;
  int lm = lane & 15, lq = lane >> 4;
  int wm = (wave >> 1) * 64, wn = (wave & 1) * 64;
  int rloc = lane >> 3;
  int c_st = (lane & 7) * 8;
  floatx4 acc[4][4] = {};

  for (int k0 = 0; k0 < K; k0 += 64) {
    __syncthreads();
    #pragma unroll
    for (int j = 0; j < 4; j++) {
      int t = wave * 4 + j;
      const ushortT* ga = Abase + (size_t)(t * 8 + rloc) * K + k0 + c_st;
      const ushortT* gb = Bbase + (size_t)(t * 8 + rloc) * K + k0 + c_st;
      __builtin_amdgcn_global_load_lds((const __attribute__((address_space(1))) void*)ga,
                                       (__attribute__((address_space(3))) void*)(As + t * 512),
                                       16, 0, 0);
      __builtin_amdgcn_global_load_lds((const __attribute__((address_space(1))) void*)gb,
                                       (__attribute__((address_space(3))) void*)(Bs + t * 512),
                                       16, 0, 0);
    }
    __syncthreads();
    #pragma unroll
    for (int ks = 0; ks < 2; ks++) {
      short8 af[4], bfv[4];
      #pragma unroll
      for (int i = 0; i < 4; i++)
        af[i] = *(const short8*)(As + (wm + i * 16 + lm) * 64 + ks * 32 + lq * 8);
      #pragma unroll
      for (int j2 = 0; j2 < 4; j2++)
        bfv[j2] = *(const short8*)(Bs + (wn + j2 * 16 + lm) * 64 + ks * 32 + lq * 8);
      #pragma unroll
      for (int i = 0; i < 4; i++)
        #pragma unroll
        for (int j2 = 0; j2 < 4; j2++)
          acc[i][j2] = __builtin_amdgcn_mfma_f32_16x16x32_bf16(af[i], bfv[j2], acc[i][j2], 0, 0, 0);
    }
  }
  #pragma unroll
  for (int i = 0; i < 4; i++) {
    #pragma unroll
    for (int j2 = 0; j2 < 4; j2++) {
      int mg = bm * 128 + wm + i * 16 + lq * 4;
      int ng = bn * 128 + wn + j2 * 16 + lm;
      #pragma unroll
      for (int q = 0; q < 4; q++) {
        size_t off = (size_t)(mg + q) * N + ng;
        if (out_bf16) Cb[off] = f2bf(acc[i][j2][q]);
        else          Cf[off] = acc[i][j2][q];
      }
    }
  }
}

// ---------------- causal depthwise conv(k=4) + silu, bf16 in/out ----------------
// Thread owns permuted-contiguous ushort4 at p4 = w*64+c: plain l0 = c*64 + w*4.
__global__ __launch_bounds__(256) void conv_silu_kernel(const ushortT* __restrict__ xz,
                                                        const float* __restrict__ w,
                                                        const float* __restrict__ bias,
                                                        ushortT* __restrict__ xc, int reverse)
{
  int idx = blockIdx.x * 256 + threadIdx.x;
  int p4 = idx & 1023;
  int rb = idx >> 10;
  int b = rb & 3, d = rb >> 2;
  int wq = p4 >> 6, c = p4 & 63;
  int l0 = c * 64 + wq * 4;                    // plain (or reversed-seq) position
  const ushortT* xin = xz + (size_t)d * NCOLS + b * L_SZ;
  float w0 = w[d * 4], w1 = w[d * 4 + 1], w2 = w[d * 4 + 2], w3 = w[d * 4 + 3];
  float bv = bias[d];
  float xv[8];
  float r0, r1, r2, r3;
  if (!reverse) {
    if (l0 >= 4) {
      ushort4 a = *(const ushort4*)(xin + l0 - 4);
      ushort4 cc = *(const ushort4*)(xin + l0);
      xv[0]=bf2f(a.x); xv[1]=bf2f(a.y); xv[2]=bf2f(a.z); xv[3]=bf2f(a.w);
      xv[4]=bf2f(cc.x); xv[5]=bf2f(cc.y); xv[6]=bf2f(cc.z); xv[7]=bf2f(cc.w);
    } else {
      #pragma unroll
      for (int i = 0; i < 8; i++) { int p = l0 - 4 + i; xv[i] = (p >= 0) ? bf2f(xin[p]) : 0.f; }
    }
    r0 = bv + w0*xv[1] + w1*xv[2] + w2*xv[3] + w3*xv[4];
    r1 = bv + w0*xv[2] + w1*xv[3] + w2*xv[4] + w3*xv[5];
    r2 = bv + w0*xv[3] + w1*xv[4] + w2*xv[5] + w3*xv[6];
    r3 = bv + w0*xv[4] + w1*xv[5] + w2*xv[6] + w3*xv[7];
  } else {
    int base = 4092 - l0;
    if (l0 >= 4) {
      ushort4 a = *(const ushort4*)(xin + base);
      ushort4 cc = *(const ushort4*)(xin + base + 4);
      xv[0]=bf2f(a.x); xv[1]=bf2f(a.y); xv[2]=bf2f(a.z); xv[3]=bf2f(a.w);
      xv[4]=bf2f(cc.x); xv[5]=bf2f(cc.y); xv[6]=bf2f(cc.z); xv[7]=bf2f(cc.w);
    } else {
      #pragma unroll
      for (int i = 0; i < 8; i++) { int p = base + i; xv[i] = (p <= 4095) ? bf2f(xin[p]) : 0.f; }
    }
    r0 = bv + w0*xv[6] + w1*xv[5] + w2*xv[4] + w3*xv[3];
    r1 = bv + w0*xv[5] + w1*xv[4] + w2*xv[3] + w3*xv[2];
    r2 = bv + w0*xv[4] + w1*xv[3] + w2*xv[2] + w3*xv[1];
    r3 = bv + w0*xv[3] + w1*xv[2] + w2*xv[1] + w3*xv[0];
  }
  ushort4 o;
  o.x = f2bf(r0 / (1.f + __expf(-r0)));
  o.y = f2bf(r1 / (1.f + __expf(-r1)));
  o.z = f2bf(r2 / (1.f + __expf(-r2)));
  o.w = f2bf(r3 / (1.f + __expf(-r3)));
  *(ushort4*)(xc + (size_t)d * NCOLS + b * L_SZ + p4 * 4) = o;
}

// ---------------- x_proj GEMM (fp32 vector): 80 x NCOLS from xc(bf16) ----------------
__global__ __launch_bounds__(256) void xdbl_kernel(const ushortT* __restrict__ xc,
                                                   const float* __restrict__ W, // (80,1536)
                                                   float* __restrict__ dtr,
                                                   float* __restrict__ Bt,
                                                   float* __restrict__ Ct)
{
  __shared__ float xcs[32 * 68];
  __shared__ float Ws[80 * 32];
  int tid = threadIdx.x;
  int n0 = blockIdx.x * 64;
  int tm = tid >> 4, tn = tid & 15;
  float acc[5][4] = {};
  for (int k0 = 0; k0 < DINNER; k0 += 32) {
    __syncthreads();
    {
      int kk = tid >> 3, c8 = (tid & 7) * 8;
      const ushortT* src = xc + (size_t)(k0 + kk) * NCOLS + n0 + c8;
      ushort4 a = *(const ushort4*)src;
      ushort4 b = *(const ushort4*)(src + 4);
      float* dst = xcs + kk * 68 + c8;
      dst[0]=bf2f(a.x); dst[1]=bf2f(a.y); dst[2]=bf2f(a.z); dst[3]=bf2f(a.w);
      dst[4]=bf2f(b.x); dst[5]=bf2f(b.y); dst[6]=bf2f(b.z); dst[7]=bf2f(b.w);
    }
    for (int i = tid; i < 80 * 32; i += 256) {
      int m = i >> 5, kk = i & 31;
      Ws[i] = W[(size_t)m * DINNER + k0 + kk];
    }
    __syncthreads();
    #pragma unroll 8
    for (int kk = 0; kk < 32; kk++) {
      const float* xr = xcs + kk * 68 + tn * 4;
      float x0 = xr[0], x1 = xr[1], x2 = xr[2], x3 = xr[3];
      #pragma unroll
      for (int im = 0; im < 5; im++) {
        float wv = Ws[(tm * 5 + im) * 32 + kk];
        acc[im][0] += wv * x0; acc[im][1] += wv * x1;
        acc[im][2] += wv * x2; acc[im][3] += wv * x3;
      }
    }
  }
  #pragma unroll
  for (int im = 0; im < 5; im++) {
    int m = tm * 5 + im;
    #pragma unroll
    for (int j = 0; j < 4; j++) {
      int n = n0 + tn * 4 + j;
      float v = acc[im][j];
      if (m < 48)      dtr[(size_t)m * NCOLS + n] = v;
      else if (m < 64) Bt[(size_t)n * 16 + (m - 48)] = v;
      else             Ct[(size_t)n * 16 + (m - 64)] = v;
    }
  }
}

// ---------------- dt = softplus(W @ dtr + bias), bf16 out (permuted cols) ----------------
// Tiled GEMM: M=1536, N=16384, K=48. Block = 64x64 tile, thread = 4x4 micro-tile.
// Grid (NCOLS/64, DINNER/64) = (256, 24).
__global__ __launch_bounds__(256) void dt_kernel(const float* __restrict__ dtr,
                                                 const float* __restrict__ W, // (1536,48)
                                                 const float* __restrict__ bias,
                                                 ushortT* __restrict__ dtb)
{
  __shared__ float sD[48 * 68];   // dtr tile [k][n], +4 pad
  __shared__ float sW[48 * 68];   // W tile transposed [k][d], +4 pad
  int tid = threadIdx.x;
  int n0 = blockIdx.x * 64, d0 = blockIdx.y * 64;
  for (int i = tid; i < 48 * 64; i += 256) {
    int r = i >> 6, c = i & 63;
    sD[r * 68 + c] = dtr[(size_t)r * NCOLS + n0 + c];
  }
  for (int i = tid; i < 64 * 48; i += 256) {
    int dd = i / 48, k = i - dd * 48;          // contiguous global read W[d0*48 + i]
    sW[k * 68 + dd] = W[(size_t)d0 * 48 + i];
  }
  __syncthreads();
  int tn = tid & 15, tm = tid >> 4;
  float acc[4][4];
  #pragma unroll
  for (int i = 0; i < 4; i++) {
    float bv = bias[d0 + tm * 4 + i];
    #pragma unroll
    for (int j = 0; j < 4; j++) acc[i][j] = bv;
  }
  #pragma unroll 6
  for (int k = 0; k < 48; k++) {
    float4 wv = *(const float4*)(sW + k * 68 + tm * 4);
    float4 xv = *(const float4*)(sD + k * 68 + tn * 4);
    float wa[4] = { wv.x, wv.y, wv.z, wv.w };
    float xa[4] = { xv.x, xv.y, xv.z, xv.w };
    #pragma unroll
    for (int i = 0; i < 4; i++)
      #pragma unroll
      for (int j = 0; j < 4; j++)
        acc[i][j] += wa[i] * xa[j];
  }
  #pragma unroll
  for (int i = 0; i < 4; i++) {
    int d = d0 + tm * 4 + i;
    ushort4 o;
    float a0 = acc[i][0], a1 = acc[i][1], a2 = acc[i][2], a3 = acc[i][3];
    o.x = f2bf((a0 > 20.f) ? a0 : log1pf(__expf(a0)));
    o.y = f2bf((a1 > 20.f) ? a1 : log1pf(__expf(a1)));
    o.z = f2bf((a2 > 20.f) ? a2 : log1pf(__expf(a2)));
    o.w = f2bf((a3 > 20.f) ? a3 : log1pf(__expf(a3)));
    *(ushort4*)(dtb + (size_t)d * NCOLS + n0 + tn * 4) = o;
  }
}

// ---------------- chunked selective scan v3 ----------------
// Block 256 = 2 d-rows x 64 chunks x 2 state-halves (8 states/thread).
// Grid (DINNER/2, B_SZ) = (768,4) -> 12 blocks/CU.
__global__ __launch_bounds__(256) void scan_kernel3(const ushortT* __restrict__ u,
                                                    const ushortT* __restrict__ dt,
                                                    const float* __restrict__ Bt,
                                                    const float* __restrict__ Ct,
                                                    const float* __restrict__ A_log,
                                                    const float* __restrict__ Dp,
                                                    ushortT* __restrict__ y, int reverse)
{
  __shared__ float Ps[32 * 65];
  __shared__ float Hs[32 * 65];
  int tid = threadIdx.x;
  int hf = tid & 1;                  // state half
  int c  = (tid >> 1) & 63;          // chunk
  int dl = tid >> 7;                 // d-row within block (0,1)
  int b = blockIdx.y;
  int d = blockIdx.x * 2 + dl;
  int ns0 = hf * 8;

  float Av2[8];
  #pragma unroll
  for (int n = 0; n < 8; n++)
    Av2[n] = -__expf(A_log[d * 16 + ns0 + n]) * 1.442695040888963f;  // A*log2(e)
  float Dv = Dp[d];

  const ushortT* ur = u  + (size_t)d * NCOLS + b * L_SZ + c * 4;
  const ushortT* tr = dt + (size_t)d * NCOLS + b * L_SZ + c * 4;
  const float*   Bp = Bt + (size_t)b * L_SZ * 16 + ns0;
  const float*   Cp = Ct + (size_t)b * L_SZ * 16 + ns0;

  float h[8];
  float S = 0.f;
  #pragma unroll
  for (int n = 0; n < 8; n++) h[n] = 0.f;

  // ---- pass 1: chunk summaries ----
  for (int w = 0; w < 16; w++) {
    ushort4 u4 = *(const ushort4*)(ur + w * 256);
    ushort4 t4 = *(const ushort4*)(tr + w * 256);
    float uv[4] = { bf2f(u4.x), bf2f(u4.y), bf2f(u4.z), bf2f(u4.w) };
    float tv[4] = { bf2f(t4.x), bf2f(t4.y), bf2f(t4.z), bf2f(t4.w) };
    #pragma unroll
    for (int q = 0; q < 4; q++) {
      float dtu = tv[q] * uv[q];
      int pl = w * 256 + c * 4 + q;
      const float4* bp4 = (const float4*)(Bp + pl * 16);
      float4 b0 = bp4[0], b1 = bp4[1];
      float Bf[8] = { b0.x,b0.y,b0.z,b0.w, b1.x,b1.y,b1.z,b1.w };
      #pragma unroll
      for (int n = 0; n < 8; n++) {
        float e = exp2f(tv[q] * Av2[n]);
        h[n] = h[n] * e + Bf[n] * dtu;
      }
      S += tv[q];
    }
  }

  #pragma unroll
  for (int n = 0; n < 8; n++) {
    int row = dl * 16 + ns0 + n;
    Ps[row * 65 + c] = exp2f(Av2[n] * S);
    Hs[row * 65 + c] = h[n];
  }
  __syncthreads();

  // ---- combine: 32 threads = (d-row, state); serial over 64 chunks ----
  if (tid < 32) {
    int row = tid;
    float hs = 0.f;
    for (int cc = 0; cc < NCHUNK; cc++) {
      int idx = row * 65 + cc;
      float tmp = Hs[idx];
      Hs[idx] = hs;                   // h at chunk start
      hs = Ps[idx] * hs + tmp;        // h at chunk end
    }
  }
  __syncthreads();
  #pragma unroll
  for (int n = 0; n < 8; n++) h[n] = Hs[(dl * 16 + ns0 + n) * 65 + c];

  // ---- pass 2: recompute h from h_start, emit y in PERMUTED layout ----
  ushortT* yrow = y + (size_t)d * NCOLS + b * L_SZ;
  for (int w = 0; w < 16; w++) {
    ushort4 u4 = *(const ushort4*)(ur + w * 256);
    ushort4 t4 = *(const ushort4*)(tr + w * 256);
    float uv[4] = { bf2f(u4.x), bf2f(u4.y), bf2f(u4.z), bf2f(u4.w) };
    float tv[4] = { bf2f(t4.x), bf2f(t4.y), bf2f(t4.z), bf2f(t4.w) };
    float yo[4];
    #pragma unroll
    for (int q = 0; q < 4; q++) {
      float dtu = tv[q] * uv[q];
      int pl = w * 256 + c * 4 + q;
      const float4* bp4 = (const float4*)(Bp + pl * 16);
      const float4* cp4 = (const float4*)(Cp + pl * 16);
      float4 b0 = bp4[0], b1 = bp4[1];
      float4 c0 = cp4[0], c1 = cp4[1];
      float Bf[8] = { b0.x,b0.y,b0.z,b0.w, b1.x,b1.y,b1.z,b1.w };
      float Cv[8] = { c0.x,c0.y,c0.z,c0.w, c1.x,c1.y,c1.z,c1.w };
      float acc = 0.f;
      #pragma unroll
      for (int n = 0; n < 8; n++) {
        float e = exp2f(tv[q] * Av2[n]);
        h[n] = h[n] * e + Bf[n] * dtu;
        acc += h[n] * Cv[n];
      }
      acc += __shfl_xor(acc, 1);       // combine the two state-halves
      yo[q] = acc + Dv * uv[q];
    }
    if (hf == 0) {
      if (!reverse) {
        ushort4 o;
        o.x = f2bf(yo[0]); o.y = f2bf(yo[1]); o.z = f2bf(yo[2]); o.w = f2bf(yo[3]);
        *(ushort4*)(yrow + w * 256 + c * 4) = o;
      } else {
        // plain l = 4095 - lrev maps to permuted (15-w)*256 + (63-c)*4 + (3-q)
        ushort4* dst = (ushort4*)(yrow + (15 - w) * 256 + (63 - c) * 4);
        ushort4 old = *dst;
        ushort4 o;
        o.x = f2bf(bf2f(old.x) + yo[3]);
        o.y = f2bf(bf2f(old.y) + yo[2]);
        o.z = f2bf(bf2f(old.z) + yo[1]);
        o.w = f2bf(bf2f(old.w) + yo[0]);
        *dst = o;
      }
    }
  }
}

// ---------------- inner = bf16( y * silu(z) ), transposed to (n, d) ----------------
// y is in permuted layout; z (xz) and output are plain.
__global__ __launch_bounds__(256) void inner_kernel(const ushortT* __restrict__ y,
                                                    const ushortT* __restrict__ xz,
                                                    ushortT* __restrict__ innerb)
{
  __shared__ float tile[64 * 65];
  int n0 = blockIdx.x * 64, d0 = blockIdx.y * 64;
  int tid = threadIdx.x;
  int c = tid & 63, rq = tid >> 6;
  int bseg = n0 & ~4095;                        // b * L_SZ
  int cch = (n0 & 4095) >> 6;                   // chunk (fixed for this tile)
  int poff = bseg + cch * 4 + (c >> 2) * 256 + (c & 3);  // permuted column of plain n0+c
  #pragma unroll
  for (int r = 0; r < 16; r++) {
    int dd = rq + r * 4;
    float yv = bf2f(y[(size_t)(d0 + dd) * NCOLS + poff]);
    float zv = bf2f(xz[(size_t)(DINNER + d0 + dd) * NCOLS + n0 + c]);
    float sv = zv / (1.f + __expf(-zv));
    tile[dd * 65 + c] = yv * sv;
  }
  __syncthreads();
  #pragma unroll
  for (int r = 0; r < 16; r++) {
    int nn = rq + r * 4;
    innerb[(size_t)(n0 + nn) * DINNER + d0 + c] = f2bf(tile[c * 65 + nn]);
  }
}

extern "C" void kernel_launch(void* const* d_in, const int* in_sizes, int n_in,
                              void* d_out, int out_size, void* d_ws, size_t ws_size,
                              hipStream_t stream)
{
  const float* x          = (const float*)d_in[0];
  const float* in_proj_w  = (const float*)d_in[1];
  const float* out_proj_w = (const float*)d_in[2];
  const float* conv_w     = (const float*)d_in[3];
  const float* conv_b     = (const float*)d_in[4];
  const float* xproj_w    = (const float*)d_in[5];
  const float* dt_w       = (const float*)d_in[6];
  const float* dt_b       = (const float*)d_in[7];
  const float* A_log      = (const float*)d_in[8];
  const float* Dp         = (const float*)d_in[9];
  const float* conv_w_b   = (const float*)d_in[10];
  const float* conv_b_b   = (const float*)d_in[11];
  const float* xproj_w_b  = (const float*)d_in[12];
  const float* dt_w_b     = (const float*)d_in[13];
  const float* dt_b_b     = (const float*)d_in[14];
  const float* A_log_b    = (const float*)d_in[15];
  const float* D_b        = (const float*)d_in[16];

  // --- workspace layout (peak 199.25 MiB), DTB in d_out ---
  char* ws = (char*)d_ws;
  ushortT* XZ   = (ushortT*)(ws + 0);
  ushortT* XC   = (ushortT*)(ws + 100663296);
  ushortT* YB   = (ushortT*)(ws + 150994944);
  float*   DTR  = (float*)  (ws + 201326592);
  float*   BT   = (float*)  (ws + 204472320);
  float*   CT   = (float*)  (ws + 205520896);
  ushortT* WOB  = (ushortT*)(ws + 206569472);
  ushortT* XB   = (ushortT*)(ws + 100663296);  // overlay on XC region (P0/P1 only)
  ushortT* WIB  = (ushortT*)(ws + 150994944);  // overlay on YB region (P0/P1 only)
  ushortT* DTB  = (ushortT*)d_out;             // 48 MiB exactly
  ushortT* INNER = XZ;                         // overlay on XZ x-half
  float* OUT = (float*)d_out;

  // bf16 conversions
  cvt_bf16_kernel<<<12288, 256, 0, stream>>>(x, XB, 3145728);
  cvt_bf16_kernel<<<2304, 256, 0, stream>>>(in_proj_w, WIB, 589824);
  cvt_bf16_kernel<<<1152, 256, 0, stream>>>(out_proj_w, WOB, 294912);

  // xz = in_proj_w @ x^T : (3072 x 16384), bf16 out; G=16 swizzle for L2 reuse
  gemm_nt<<<dim3(128, 24), 256, 0, stream>>>(WIB, XB, nullptr, XZ, E2, NCOLS, DIM, 1, 16);

  // forward direction
  conv_silu_kernel<<<24576, 256, 0, stream>>>(XZ, conv_w, conv_b, XC, 0);
  xdbl_kernel<<<256, 256, 0, stream>>>(XC, xproj_w, DTR, BT, CT);
  dt_kernel<<<dim3(256, 24), 256, 0, stream>>>(DTR, dt_w, dt_b, DTB);
  scan_kernel3<<<dim3(768, 4), 256, 0, stream>>>(XC, DTB, BT, CT, A_log, Dp, YB, 0);

  // reverse direction (reversed coords; y added at original positions, permuted layout)
  conv_silu_kernel<<<24576, 256, 0, stream>>>(XZ, conv_w_b, conv_b_b, XC, 1);
  xdbl_kernel<<<256, 256, 0, stream>>>(XC, xproj_w_b, DTR, BT, CT);
  dt_kernel<<<dim3(256, 24), 256, 0, stream>>>(DTR, dt_w_b, dt_b_b, DTB);
  scan_kernel3<<<dim3(768, 4), 256, 0, stream>>>(XC, DTB, BT, CT, A_log_b, D_b, YB, 1);

  // inner = bf16( y * silu(z) ) transposed to (n, d); un-permutes y
  inner_kernel<<<dim3(256, 24), 256, 0, stream>>>(YB, XZ, INNER);

  // out = inner @ out_proj_w^T : (16384 x 768), fp32 out
  gemm_nt<<<dim3(6, 128), 256, 0, stream>>>(INNER, WOB, OUT, nullptr, NCOLS, DIM, DINNER, 0, 6);
}

// Round 7
// 1761.330 us; speedup vs baseline: 1.8774x; 1.1494x over previous
//
#include <hip/hip_runtime.h>

#define L_SZ   4096
#define B_SZ   4
#define NCOLS  16384      // B_SZ * L_SZ
#define DIM    768
#define DINNER 1536
#define E2     3072       // 2*DINNER
#define DTRANK 48
#define DSTATE 16
#define NCHUNK 64
#define CLEN   64         // L_SZ / NCHUNK

// perm within each (d,b) 4096-row: l = c*64 + w*4 + q  ->  off = w*256 + c*4 + q

typedef unsigned short ushortT;
typedef __attribute__((ext_vector_type(8))) short short8;
typedef __attribute__((ext_vector_type(4))) float floatx4;

__device__ __forceinline__ unsigned short f2bf(float f) {
  union { float f; unsigned u; } v; v.f = f;
  unsigned r = v.u + 0x7FFF + ((v.u >> 16) & 1);
  return (unsigned short)(r >> 16);
}
__device__ __forceinline__ float bf2f(unsigned short h) {
  union { unsigned u; float f; } v; v.u = ((unsigned)h) << 16;
  return v.f;
}

// ---------------- fp32 -> bf16 conversion ----------------
__global__ __launch_bounds__(256) void cvt_bf16_kernel(const float* __restrict__ in,
                                                       ushortT* __restrict__ out, int n4) {
  int i = blockIdx.x * 256 + threadIdx.x;
  if (i >= n4) return;
  float4 v = ((const float4*)in)[i];
  ushort4 o;
  o.x = f2bf(v.x); o.y = f2bf(v.y); o.z = f2bf(v.z); o.w = f2bf(v.w);
  ((ushort4*)out)[i] = o;
}

// ---------------- zero fill (float4 granules) ----------------
__global__ __launch_bounds__(256) void zero_kernel(float4* __restrict__ p) {
  p[blockIdx.x * 256 + threadIdx.x] = make_float4(0.f, 0.f, 0.f, 0.f);
}

// ---------------- bf16 NT GEMM: C[m,n] = sum_k A[m,k]*B[n,k] ----------------
__global__ __launch_bounds__(256) void gemm_nt(const ushortT* __restrict__ A,
                                               const ushortT* __restrict__ Bm,
                                               float* __restrict__ Cf, ushortT* __restrict__ Cb,
                                               int M, int N, int K, int out_bf16, int G)
{
  __shared__ ushortT As[128 * 64];
  __shared__ ushortT Bs[128 * 64];
  int tid = threadIdx.x;
  int wave = tid >> 6, lane = tid & 63;
  int gid = blockIdx.y * gridDim.x + blockIdx.x;
  int per_sg = G * gridDim.y;
  int sg = gid / per_sg, r = gid % per_sg;
  int bm = r / G;
  int bn = sg * G + (r % G);
  const ushortT* Abase = A + (size_t)bm * 128 * K;
  const ushortT* Bbase = Bm + (size_t)bn * 128 * K;
  int lm = lane & 15, lq = lane >> 4;
  int wm = (wave >> 1) * 64, wn = (wave & 1) * 64;
  int rloc = lane >> 3;
  int c_st = (lane & 7) * 8;
  floatx4 acc[4][4] = {};

  for (int k0 = 0; k0 < K; k0 += 64) {
    __syncthreads();
    #pragma unroll
    for (int j = 0; j < 4; j++) {
      int t = wave * 4 + j;
      const ushortT* ga = Abase + (size_t)(t * 8 + rloc) * K + k0 + c_st;
      const ushortT* gb = Bbase + (size_t)(t * 8 + rloc) * K + k0 + c_st;
      __builtin_amdgcn_global_load_lds((const __attribute__((address_space(1))) void*)ga,
                                       (__attribute__((address_space(3))) void*)(As + t * 512),
                                       16, 0, 0);
      __builtin_amdgcn_global_load_lds((const __attribute__((address_space(1))) void*)gb,
                                       (__attribute__((address_space(3))) void*)(Bs + t * 512),
                                       16, 0, 0);
    }
    __syncthreads();
    #pragma unroll
    for (int ks = 0; ks < 2; ks++) {
      short8 af[4], bfv[4];
      #pragma unroll
      for (int i = 0; i < 4; i++)
        af[i] = *(const short8*)(As + (wm + i * 16 + lm) * 64 + ks * 32 + lq * 8);
      #pragma unroll
      for (int j2 = 0; j2 < 4; j2++)
        bfv[j2] = *(const short8*)(Bs + (wn + j2 * 16 + lm) * 64 + ks * 32 + lq * 8);
      #pragma unroll
      for (int i = 0; i < 4; i++)
        #pragma unroll
        for (int j2 = 0; j2 < 4; j2++)
          acc[i][j2] = __builtin_amdgcn_mfma_f32_16x16x32_bf16(af[i], bfv[j2], acc[i][j2], 0, 0, 0);
    }
  }
  #pragma unroll
  for (int i = 0; i < 4; i++) {
    #pragma unroll
    for (int j2 = 0; j2 < 4; j2++) {
      int mg = bm * 128 + wm + i * 16 + lq * 4;
      int ng = bn * 128 + wn + j2 * 16 + lm;
      #pragma unroll
      for (int q = 0; q < 4; q++) {
        size_t off = (size_t)(mg + q) * N + ng;
        if (out_bf16) Cb[off] = f2bf(acc[i][j2][q]);
        else          Cf[off] = acc[i][j2][q];
      }
    }
  }
}

// ---------------- causal depthwise conv(k=4) + silu, bf16 in/out ----------------
__global__ __launch_bounds__(256) void conv_silu_kernel(const ushortT* __restrict__ xz,
                                                        const float* __restrict__ w,
                                                        const float* __restrict__ bias,
                                                        ushortT* __restrict__ xc, int reverse)
{
  int idx = blockIdx.x * 256 + threadIdx.x;
  int p4 = idx & 1023;
  int rb = idx >> 10;
  int b = rb & 3, d = rb >> 2;
  int wq = p4 >> 6, c = p4 & 63;
  int l0 = c * 64 + wq * 4;                    // plain (or reversed-seq) position
  const ushortT* xin = xz + (size_t)d * NCOLS + b * L_SZ;
  float w0 = w[d * 4], w1 = w[d * 4 + 1], w2 = w[d * 4 + 2], w3 = w[d * 4 + 3];
  float bv = bias[d];
  float xv[8];
  float r0, r1, r2, r3;
  if (!reverse) {
    if (l0 >= 4) {
      ushort4 a = *(const ushort4*)(xin + l0 - 4);
      ushort4 cc = *(const ushort4*)(xin + l0);
      xv[0]=bf2f(a.x); xv[1]=bf2f(a.y); xv[2]=bf2f(a.z); xv[3]=bf2f(a.w);
      xv[4]=bf2f(cc.x); xv[5]=bf2f(cc.y); xv[6]=bf2f(cc.z); xv[7]=bf2f(cc.w);
    } else {
      #pragma unroll
      for (int i = 0; i < 8; i++) { int p = l0 - 4 + i; xv[i] = (p >= 0) ? bf2f(xin[p]) : 0.f; }
    }
    r0 = bv + w0*xv[1] + w1*xv[2] + w2*xv[3] + w3*xv[4];
    r1 = bv + w0*xv[2] + w1*xv[3] + w2*xv[4] + w3*xv[5];
    r2 = bv + w0*xv[3] + w1*xv[4] + w2*xv[5] + w3*xv[6];
    r3 = bv + w0*xv[4] + w1*xv[5] + w2*xv[6] + w3*xv[7];
  } else {
    int base = 4092 - l0;
    if (l0 >= 4) {
      ushort4 a = *(const ushort4*)(xin + base);
      ushort4 cc = *(const ushort4*)(xin + base + 4);
      xv[0]=bf2f(a.x); xv[1]=bf2f(a.y); xv[2]=bf2f(a.z); xv[3]=bf2f(a.w);
      xv[4]=bf2f(cc.x); xv[5]=bf2f(cc.y); xv[6]=bf2f(cc.z); xv[7]=bf2f(cc.w);
    } else {
      #pragma unroll
      for (int i = 0; i < 8; i++) { int p = base + i; xv[i] = (p <= 4095) ? bf2f(xin[p]) : 0.f; }
    }
    r0 = bv + w0*xv[6] + w1*xv[5] + w2*xv[4] + w3*xv[3];
    r1 = bv + w0*xv[5] + w1*xv[4] + w2*xv[3] + w3*xv[2];
    r2 = bv + w0*xv[4] + w1*xv[3] + w2*xv[2] + w3*xv[1];
    r3 = bv + w0*xv[3] + w1*xv[2] + w2*xv[1] + w3*xv[0];
  }
  ushort4 o;
  o.x = f2bf(r0 / (1.f + __expf(-r0)));
  o.y = f2bf(r1 / (1.f + __expf(-r1)));
  o.z = f2bf(r2 / (1.f + __expf(-r2)));
  o.w = f2bf(r3 / (1.f + __expf(-r3)));
  *(ushort4*)(xc + (size_t)d * NCOLS + b * L_SZ + p4 * 4) = o;
}

// ---------------- x_proj GEMM (fp32 vector), K-split x3 + atomic accumulate ----------------
// grid (NCOLS/64, 3). Outputs must be pre-zeroed.
__global__ __launch_bounds__(256) void xdbl_kernel(const ushortT* __restrict__ xc,
                                                   const float* __restrict__ W, // (80,1536)
                                                   float* __restrict__ dtr,
                                                   float* __restrict__ Bt,
                                                   float* __restrict__ Ct)
{
  __shared__ float xcs[32 * 68];
  __shared__ float Ws[80 * 32];
  int tid = threadIdx.x;
  int n0 = blockIdx.x * 64;
  int kbase = blockIdx.y * 512;
  int tm = tid >> 4, tn = tid & 15;
  float acc[5][4] = {};
  for (int k0 = kbase; k0 < kbase + 512; k0 += 32) {
    __syncthreads();
    {
      int kk = tid >> 3, c8 = (tid & 7) * 8;
      const ushortT* src = xc + (size_t)(k0 + kk) * NCOLS + n0 + c8;
      ushort4 a = *(const ushort4*)src;
      ushort4 b = *(const ushort4*)(src + 4);
      float* dst = xcs + kk * 68 + c8;
      dst[0]=bf2f(a.x); dst[1]=bf2f(a.y); dst[2]=bf2f(a.z); dst[3]=bf2f(a.w);
      dst[4]=bf2f(b.x); dst[5]=bf2f(b.y); dst[6]=bf2f(b.z); dst[7]=bf2f(b.w);
    }
    for (int i = tid; i < 80 * 32; i += 256) {
      int m = i >> 5, kk = i & 31;
      Ws[i] = W[(size_t)m * DINNER + k0 + kk];
    }
    __syncthreads();
    #pragma unroll 8
    for (int kk = 0; kk < 32; kk++) {
      const float* xr = xcs + kk * 68 + tn * 4;
      float x0 = xr[0], x1 = xr[1], x2 = xr[2], x3 = xr[3];
      #pragma unroll
      for (int im = 0; im < 5; im++) {
        float wv = Ws[(tm * 5 + im) * 32 + kk];
        acc[im][0] += wv * x0; acc[im][1] += wv * x1;
        acc[im][2] += wv * x2; acc[im][3] += wv * x3;
      }
    }
  }
  #pragma unroll
  for (int im = 0; im < 5; im++) {
    int m = tm * 5 + im;
    #pragma unroll
    for (int j = 0; j < 4; j++) {
      int n = n0 + tn * 4 + j;
      float v = acc[im][j];
      if (m < 48)      atomicAdd(&dtr[(size_t)m * NCOLS + n], v);
      else if (m < 64) atomicAdd(&Bt[(size_t)n * 16 + (m - 48)], v);
      else             atomicAdd(&Ct[(size_t)n * 16 + (m - 64)], v);
    }
  }
}

// ---------------- dt = softplus(W @ dtr + bias), bf16 out (permuted cols) ----------------
__global__ __launch_bounds__(256) void dt_kernel(const float* __restrict__ dtr,
                                                 const float* __restrict__ W, // (1536,48)
                                                 const float* __restrict__ bias,
                                                 ushortT* __restrict__ dtb)
{
  __shared__ float sD[48 * 68];
  __shared__ float sW[48 * 68];
  int tid = threadIdx.x;
  int n0 = blockIdx.x * 64, d0 = blockIdx.y * 64;
  for (int i = tid; i < 48 * 64; i += 256) {
    int r = i >> 6, c = i & 63;
    sD[r * 68 + c] = dtr[(size_t)r * NCOLS + n0 + c];
  }
  for (int i = tid; i < 64 * 48; i += 256) {
    int dd = i / 48, k = i - dd * 48;
    sW[k * 68 + dd] = W[(size_t)d0 * 48 + i];
  }
  __syncthreads();
  int tn = tid & 15, tm = tid >> 4;
  float acc[4][4];
  #pragma unroll
  for (int i = 0; i < 4; i++) {
    float bv = bias[d0 + tm * 4 + i];
    #pragma unroll
    for (int j = 0; j < 4; j++) acc[i][j] = bv;
  }
  #pragma unroll 6
  for (int k = 0; k < 48; k++) {
    float4 wv = *(const float4*)(sW + k * 68 + tm * 4);
    float4 xv = *(const float4*)(sD + k * 68 + tn * 4);
    float wa[4] = { wv.x, wv.y, wv.z, wv.w };
    float xa[4] = { xv.x, xv.y, xv.z, xv.w };
    #pragma unroll
    for (int i = 0; i < 4; i++)
      #pragma unroll
      for (int j = 0; j < 4; j++)
        acc[i][j] += wa[i] * xa[j];
  }
  #pragma unroll
  for (int i = 0; i < 4; i++) {
    int d = d0 + tm * 4 + i;
    ushort4 o;
    float a0 = acc[i][0], a1 = acc[i][1], a2 = acc[i][2], a3 = acc[i][3];
    o.x = f2bf((a0 > 20.f) ? a0 : log1pf(__expf(a0)));
    o.y = f2bf((a1 > 20.f) ? a1 : log1pf(__expf(a1)));
    o.z = f2bf((a2 > 20.f) ? a2 : log1pf(__expf(a2)));
    o.w = f2bf((a3 > 20.f) ? a3 : log1pf(__expf(a3)));
    *(ushort4*)(dtb + (size_t)d * NCOLS + n0 + tn * 4) = o;
  }
}

// ---------------- chunked selective scan v4: closed-form pass-2 correction ----------------
// Block 256 = 2 d-rows x 64 chunks x 2 state-halves (8 states/thread).
// Pass 1: zero-state y1 = C.h0 + D.u, stored bf16 IN-PLACE over u (owner-exclusive);
//         chunk summaries h0_end (Hs) and S = sum(dt) (Ss).
// Combine: h_start per chunk (P recomputed from S on the fly).
// Pass 2 (chain-free): y = y1 + sum_n C[l,n] * exp2(Av2[n]*T_l) * h_start[n],
//         T_l = inclusive in-chunk cumsum of dt.
// Grid (DINNER/2, B_SZ) = (768,4).
__global__ __launch_bounds__(256) void scan_kernel4(ushortT* __restrict__ u,   // XC, y1 in-place
                                                    const ushortT* __restrict__ dt,
                                                    const float* __restrict__ Bt,
                                                    const float* __restrict__ Ct,
                                                    const float* __restrict__ A_log,
                                                    const float* __restrict__ Dp,
                                                    ushortT* __restrict__ y, int reverse)
{
  __shared__ float Hs[32 * 65];
  __shared__ float Ss[2 * 64];
  int tid = threadIdx.x;
  int hf = tid & 1;                  // state half
  int c  = (tid >> 1) & 63;          // chunk
  int dl = tid >> 7;                 // d-row within block (0,1)
  int b = blockIdx.y;
  int d = blockIdx.x * 2 + dl;
  int ns0 = hf * 8;

  float Av2[8];
  #pragma unroll
  for (int n = 0; n < 8; n++)
    Av2[n] = -__expf(A_log[d * 16 + ns0 + n]) * 1.442695040888963f;  // A*log2(e)
  float Dv = Dp[d];

  ushortT* ur = u + (size_t)d * NCOLS + b * L_SZ + c * 4;
  const ushortT* tr = dt + (size_t)d * NCOLS + b * L_SZ + c * 4;
  const float*   Bp = Bt + (size_t)b * L_SZ * 16 + ns0;
  const float*   Cp = Ct + (size_t)b * L_SZ * 16 + ns0;

  float h[8];
  float S = 0.f;
  #pragma unroll
  for (int n = 0; n < 8; n++) h[n] = 0.f;

  // ---- pass 1: y1 + chunk summaries ----
  for (int w = 0; w < 16; w++) {
    ushort4 u4 = *(const ushort4*)(ur + w * 256);
    ushort4 t4 = *(const ushort4*)(tr + w * 256);
    float uv[4] = { bf2f(u4.x), bf2f(u4.y), bf2f(u4.z), bf2f(u4.w) };
    float tv[4] = { bf2f(t4.x), bf2f(t4.y), bf2f(t4.z), bf2f(t4.w) };
    float yo[4];
    #pragma unroll
    for (int q = 0; q < 4; q++) {
      float dtu = tv[q] * uv[q];
      int pl = w * 256 + c * 4 + q;
      const float4* bp4 = (const float4*)(Bp + pl * 16);
      const float4* cp4 = (const float4*)(Cp + pl * 16);
      float4 b0 = bp4[0], b1 = bp4[1];
      float4 c0 = cp4[0], c1 = cp4[1];
      float Bf[8] = { b0.x,b0.y,b0.z,b0.w, b1.x,b1.y,b1.z,b1.w };
      float Cv[8] = { c0.x,c0.y,c0.z,c0.w, c1.x,c1.y,c1.z,c1.w };
      float acc = 0.f;
      #pragma unroll
      for (int n = 0; n < 8; n++) {
        float e = exp2f(tv[q] * Av2[n]);
        h[n] = h[n] * e + Bf[n] * dtu;
        acc += h[n] * Cv[n];
      }
      acc += __shfl_xor(acc, 1);
      yo[q] = acc + Dv * uv[q];
      S += tv[q];
    }
    if (hf == 0) {
      ushort4 o;
      o.x = f2bf(yo[0]); o.y = f2bf(yo[1]); o.z = f2bf(yo[2]); o.w = f2bf(yo[3]);
      *(ushort4*)(ur + w * 256) = o;               // y1 in-place over u
    }
  }
  #pragma unroll
  for (int n = 0; n < 8; n++)
    Hs[(dl * 16 + ns0 + n) * 65 + c] = h[n];
  if (hf == 0) Ss[dl * 64 + c] = S;
  __syncthreads();

  // ---- combine: 32 threads = (d-row, state); serial over 64 chunks ----
  if (tid < 32) {
    int dl2 = tid >> 4, n2 = tid & 15;
    float Ac = -__expf(A_log[(blockIdx.x * 2 + dl2) * 16 + n2]) * 1.442695040888963f;
    float hsv = 0.f;
    int row = tid;
    for (int cc = 0; cc < NCHUNK; cc++) {
      int idx = row * 65 + cc;
      float tmp = Hs[idx];
      Hs[idx] = hsv;                   // h at chunk start
      hsv = exp2f(Ac * Ss[dl2 * 64 + cc]) * hsv + tmp;
    }
  }
  __syncthreads();
  float hsr[8];
  #pragma unroll
  for (int n = 0; n < 8; n++) hsr[n] = Hs[(dl * 16 + ns0 + n) * 65 + c];

  // ---- pass 2 (chain-free): y = y1 + C . (exp2(Av2*T) ⊙ h_start) ----
  ushortT* yrow = y + (size_t)d * NCOLS + b * L_SZ;
  float T = 0.f;
  for (int w = 0; w < 16; w++) {
    ushort4 t4  = *(const ushort4*)(tr + w * 256);
    ushort4 y14 = *(const ushort4*)(ur + w * 256);
    float tv[4]  = { bf2f(t4.x), bf2f(t4.y), bf2f(t4.z), bf2f(t4.w) };
    float y1v[4] = { bf2f(y14.x), bf2f(y14.y), bf2f(y14.z), bf2f(y14.w) };
    float yo[4];
    #pragma unroll
    for (int q = 0; q < 4; q++) {
      T += tv[q];
      int pl = w * 256 + c * 4 + q;
      const float4* cp4 = (const float4*)(Cp + pl * 16);
      float4 c0 = cp4[0], c1 = cp4[1];
      float Cv[8] = { c0.x,c0.y,c0.z,c0.w, c1.x,c1.y,c1.z,c1.w };
      float corr = 0.f;
      #pragma unroll
      for (int n = 0; n < 8; n++)
        corr += (exp2f(Av2[n] * T) * hsr[n]) * Cv[n];
      corr += __shfl_xor(corr, 1);
      yo[q] = y1v[q] + corr;
    }
    if (hf == 0) {
      if (!reverse) {
        ushort4 o;
        o.x = f2bf(yo[0]); o.y = f2bf(yo[1]); o.z = f2bf(yo[2]); o.w = f2bf(yo[3]);
        *(ushort4*)(yrow + w * 256 + c * 4) = o;
      } else {
        // plain l = 4095 - lrev maps to permuted (15-w)*256 + (63-c)*4 + (3-q)
        ushort4* dst = (ushort4*)(yrow + (15 - w) * 256 + (63 - c) * 4);
        ushort4 old = *dst;
        ushort4 o;
        o.x = f2bf(bf2f(old.x) + yo[3]);
        o.y = f2bf(bf2f(old.y) + yo[2]);
        o.z = f2bf(bf2f(old.z) + yo[1]);
        o.w = f2bf(bf2f(old.w) + yo[0]);
        *dst = o;
      }
    }
  }
}

// ---------------- inner = bf16( y * silu(z) ), transposed to (n, d) ----------------
__global__ __launch_bounds__(256) void inner_kernel(const ushortT* __restrict__ y,
                                                    const ushortT* __restrict__ xz,
                                                    ushortT* __restrict__ innerb)
{
  __shared__ float tile[64 * 65];
  int n0 = blockIdx.x * 64, d0 = blockIdx.y * 64;
  int tid = threadIdx.x;
  int c = tid & 63, rq = tid >> 6;
  int bseg = n0 & ~4095;                        // b * L_SZ
  int cch = (n0 & 4095) >> 6;                   // chunk (fixed for this tile)
  int poff = bseg + cch * 4 + (c >> 2) * 256 + (c & 3);  // permuted column of plain n0+c
  #pragma unroll
  for (int r = 0; r < 16; r++) {
    int dd = rq + r * 4;
    float yv = bf2f(y[(size_t)(d0 + dd) * NCOLS + poff]);
    float zv = bf2f(xz[(size_t)(DINNER + d0 + dd) * NCOLS + n0 + c]);
    float sv = zv / (1.f + __expf(-zv));
    tile[dd * 65 + c] = yv * sv;
  }
  __syncthreads();
  #pragma unroll
  for (int r = 0; r < 16; r++) {
    int nn = rq + r * 4;
    innerb[(size_t)(n0 + nn) * DINNER + d0 + c] = f2bf(tile[c * 65 + nn]);
  }
}

extern "C" void kernel_launch(void* const* d_in, const int* in_sizes, int n_in,
                              void* d_out, int out_size, void* d_ws, size_t ws_size,
                              hipStream_t stream)
{
  const float* x          = (const float*)d_in[0];
  const float* in_proj_w  = (const float*)d_in[1];
  const float* out_proj_w = (const float*)d_in[2];
  const float* conv_w     = (const float*)d_in[3];
  const float* conv_b     = (const float*)d_in[4];
  const float* xproj_w    = (const float*)d_in[5];
  const float* dt_w       = (const float*)d_in[6];
  const float* dt_b       = (const float*)d_in[7];
  const float* A_log      = (const float*)d_in[8];
  const float* Dp         = (const float*)d_in[9];
  const float* conv_w_b   = (const float*)d_in[10];
  const float* conv_b_b   = (const float*)d_in[11];
  const float* xproj_w_b  = (const float*)d_in[12];
  const float* dt_w_b     = (const float*)d_in[13];
  const float* dt_b_b     = (const float*)d_in[14];
  const float* A_log_b    = (const float*)d_in[15];
  const float* D_b        = (const float*)d_in[16];

  // --- workspace layout (peak 199.25 MiB), DTB in d_out ---
  char* ws = (char*)d_ws;
  ushortT* XZ   = (ushortT*)(ws + 0);
  ushortT* XC   = (ushortT*)(ws + 100663296);
  ushortT* YB   = (ushortT*)(ws + 150994944);
  float*   DTR  = (float*)  (ws + 201326592);
  float*   BT   = (float*)  (ws + 204472320);
  float*   CT   = (float*)  (ws + 205520896);
  ushortT* WOB  = (ushortT*)(ws + 206569472);
  ushortT* XB   = (ushortT*)(ws + 100663296);  // overlay on XC region (P0/P1 only)
  ushortT* WIB  = (ushortT*)(ws + 150994944);  // overlay on YB region (P0/P1 only)
  ushortT* DTB  = (ushortT*)d_out;             // 48 MiB exactly
  ushortT* INNER = XZ;                         // overlay on XZ x-half
  float* OUT = (float*)d_out;

  // bf16 conversions
  cvt_bf16_kernel<<<12288, 256, 0, stream>>>(x, XB, 3145728);
  cvt_bf16_kernel<<<2304, 256, 0, stream>>>(in_proj_w, WIB, 589824);
  cvt_bf16_kernel<<<1152, 256, 0, stream>>>(out_proj_w, WOB, 294912);

  // xz = in_proj_w @ x^T : (3072 x 16384), bf16 out; G=16 swizzle for L2 reuse
  gemm_nt<<<dim3(128, 24), 256, 0, stream>>>(WIB, XB, nullptr, XZ, E2, NCOLS, DIM, 1, 16);

  // forward direction
  conv_silu_kernel<<<24576, 256, 0, stream>>>(XZ, conv_w, conv_b, XC, 0);
  zero_kernel<<<1280, 256, 0, stream>>>((float4*)DTR);   // DTR+BT+CT = 5 MiB
  xdbl_kernel<<<dim3(256, 3), 256, 0, stream>>>(XC, xproj_w, DTR, BT, CT);
  dt_kernel<<<dim3(256, 24), 256, 0, stream>>>(DTR, dt_w, dt_b, DTB);
  scan_kernel4<<<dim3(768, 4), 256, 0, stream>>>(XC, DTB, BT, CT, A_log, Dp, YB, 0);

  // reverse direction (reversed coords; y added at original positions, permuted layout)
  conv_silu_kernel<<<24576, 256, 0, stream>>>(XZ, conv_w_b, conv_b_b, XC, 1);
  zero_kernel<<<1280, 256, 0, stream>>>((float4*)DTR);
  xdbl_kernel<<<dim3(256, 3), 256, 0, stream>>>(XC, xproj_w_b, DTR, BT, CT);
  dt_kernel<<<dim3(256, 24), 256, 0, stream>>>(DTR, dt_w_b, dt_b_b, DTB);
  scan_kernel4<<<dim3(768, 4), 256, 0, stream>>>(XC, DTB, BT, CT, A_log_b, D_b, YB, 1);

  // inner = bf16( y * silu(z) ) transposed to (n, d); un-permutes y
  inner_kernel<<<dim3(256, 24), 256, 0, stream>>>(YB, XZ, INNER);

  // out = inner @ out_proj_w^T : (16384 x 768), fp32 out
  gemm_nt<<<dim3(6, 128), 256, 0, stream>>>(INNER, WOB, OUT, nullptr, NCOLS, DIM, DINNER, 0, 6);
}